// Round 1
// baseline (247.795 us; speedup 1.0000x reference)
//
#include <hip/hip_runtime.h>

#define TT 1024
#define HH 8
#define EE 64
#define MM 128
#define NBH 16

#define NORMALIZER 0.35355339059327379f
#define RSQRT_M    0.08838834764831845f
#define TEMP       0.125f
#define NEGINF     -1e24f

// ws byte offsets
#define OFF_QP    0u            // [BH][T][M] f32  8 MB   q_prime
#define OFF_KF    8388608u      // [BH][T][M] f32  8 MB   exp(logfeat_k) -> k_prime (in place)
#define OFF_QKV   16777216u     // [BH][T][E] f32  4 MB
#define OFF_KV    20971520u     // [BH][M][E] f32  512 KB
#define OFF_KSUM  21495808u     // [BH][M]    f32  8 KB
#define OFF_KMAX  21504000u     // [BH]       u32  64 B
#define OFF_QSTAB 21504064u     // [BH][T]    f32  64 KB
#define ZERO_SZ   (524288u + 8192u + 64u)   // kv + ksum + kmax

// ---------------------------------------------------------------------------
// Kernel A: FAVOR+ features. One lane owns one row (t); proj rows are
// wave-uniform -> scalar loads. q path: writes q_prime (stab-scaled) + qstab.
// k path: writes exp(logfeat) raw + atomicMax of exp(blockmax) per (b,h).
// grid 256 = 2 paths * 16 bh * 8 rowtiles(128), block 256.
// ---------------------------------------------------------------------------
__global__ __launch_bounds__(256) void feat_kernel(
    const float* __restrict__ Q, const float* __restrict__ K,
    const float* __restrict__ proj,
    float* __restrict__ qp, float* __restrict__ kf,
    float* __restrict__ qstab, unsigned int* __restrict__ kmax)
{
  __shared__ float C[128][132];
  __shared__ float S[128];
  __shared__ float Mh[128][2];
  __shared__ float wmax[4];

  const int bid  = blockIdx.x;
  const int path = bid >> 7;          // 0=q, 1=k
  const int bh   = (bid >> 3) & 15;
  const int rt   = bid & 7;
  const int b = bh >> 3, h = bh & 7;
  const int tid = threadIdx.x;
  const int w = __builtin_amdgcn_readfirstlane(tid >> 6);
  const int lane = tid & 63;
  const int rl = ((w & 1) << 6) + lane;     // local row 0..127
  const int mhalf = (w >> 1) << 6;          // 0 or 64
  const int t = (rt << 7) + rl;

  const float* x = path ? K : Q;
  const float4* xr = (const float4*)(x + ((((size_t)b * TT + t) * HH + h) << 6));
  float4 xv[16];
  float diag = 0.f;
#pragma unroll
  for (int c = 0; c < 16; ++c) {
    const float4 vv = xr[c];
    xv[c] = vv;
    diag += vv.x * vv.x + vv.y * vv.y + vv.z * vv.z + vv.w * vv.w;
  }
  diag *= 0.0625f;   // 0.5*temp

  float mx = -3e30f;
  const float4* pr4 = (const float4*)proj;
  for (int mm = 0; mm < 64; ++mm) {
    const int m = mhalf + mm;
    float acc = 0.f;
#pragma unroll
    for (int c = 0; c < 16; ++c) {
      const float4 p = pr4[(m << 4) + c];
      acc += xv[c].x * p.x + xv[c].y * p.y + xv[c].z * p.z + xv[c].w * p.w;
    }
    const float lf = NORMALIZER * acc - diag;
    mx = fmaxf(mx, lf);
    C[rl][m] = __expf(lf);
  }

  Mh[rl][w >> 1] = mx;
  float bm = mx;
#pragma unroll
  for (int off = 1; off < 64; off <<= 1) bm = fmaxf(bm, __shfl_xor(bm, off));
  if (lane == 0) wmax[w] = bm;
  __syncthreads();

  if (w < 2) {
    const int r = (w << 6) + lane;
    const float m0 = fmaxf(Mh[r][0], Mh[r][1]);
    if (path == 0) {
      S[r] = RSQRT_M * __expf(-m0);
      qstab[(size_t)bh * TT + (rt << 7) + r] = m0;
    } else {
      S[r] = 1.f;
    }
  }
  if (path == 1 && tid == 0) {
    const float m4 = fmaxf(fmaxf(wmax[0], wmax[1]), fmaxf(wmax[2], wmax[3]));
    atomicMax(kmax + bh, __float_as_uint(__expf(m4)));
  }
  __syncthreads();

  float* dst = (path ? kf : qp) + (((size_t)bh * TT + ((size_t)rt << 7)) << 7);
#pragma unroll
  for (int it = 0; it < 16; ++it) {
    const int idx = (it << 10) + (tid << 2);
    const int r = idx >> 7, c = idx & 127;
    float4 vv = *(const float4*)&C[r][c];
    const float s = S[r];
    vv.x *= s; vv.y *= s; vv.z *= s; vv.w *= s;
    *(float4*)&dst[idx] = vv;
  }
}

// ---------------------------------------------------------------------------
// Kernel B: k_prime = RSQRT_M * elf / max_elf (in place), ksum += sum_s kp,
// kv[m][d] += sum_s kp[s][m]*v[s][d].  grid 128 = 16 bh * 8 s-tiles(128).
// ---------------------------------------------------------------------------
__global__ __launch_bounds__(256) void kv_kernel(
    const float* __restrict__ V, float* __restrict__ kf,
    const unsigned int* __restrict__ kmax,
    float* __restrict__ kv, float* __restrict__ ksum)
{
  __shared__ __align__(16) float kp[128][132];
  __shared__ __align__(16) float vs[128][68];

  const int bid = blockIdx.x;
  const int bh = bid >> 3, st = bid & 7;
  const int b = bh >> 3, h = bh & 7;
  const int tid = threadIdx.x;
  const float scale = RSQRT_M / __uint_as_float(kmax[bh]);
  const size_t base_kf = ((size_t)bh * TT + ((size_t)st << 7)) << 7;

#pragma unroll
  for (int it = 0; it < 16; ++it) {
    const int idx = (it << 10) + (tid << 2);
    const int r = idx >> 7, c = idx & 127;
    float4 vv = *(const float4*)&kf[base_kf + idx];
    vv.x *= scale; vv.y *= scale; vv.z *= scale; vv.w *= scale;
    *(float4*)&kp[r][c] = vv;
    *(float4*)&kf[base_kf + idx] = vv;  // write back k_prime
  }
#pragma unroll
  for (int it = 0; it < 8; ++it) {
    const int idx = (it << 10) + (tid << 2);
    const int r = idx >> 6, c = idx & 63;
    const int tg = (st << 7) + r;
    *(float4*)&vs[r][c] = *(const float4*)(V + ((((size_t)b * TT + tg) * HH + h) << 6) + c);
  }
  __syncthreads();

  if (tid < 128) {
    float s = 0.f;
    for (int ss = 0; ss < 128; ++ss) s += kp[ss][tid];
    atomicAdd(&ksum[(bh << 7) + tid], s);
  }

  const int h2 = tid >> 7;                 // s half
  const int m0 = ((tid & 127) >> 3) << 3;  // 16 tiles of 8 m
  const int d0 = (tid & 7) << 3;           // 8 tiles of 8 d
  float acc[8][8];
#pragma unroll
  for (int i = 0; i < 8; ++i)
#pragma unroll
    for (int j = 0; j < 8; ++j) acc[i][j] = 0.f;

  const int s0 = h2 << 6;
  for (int ss = s0; ss < s0 + 64; ++ss) {
    const float4 k0v = *(const float4*)&kp[ss][m0];
    const float4 k1v = *(const float4*)&kp[ss][m0 + 4];
    const float4 v0v = *(const float4*)&vs[ss][d0];
    const float4 v1v = *(const float4*)&vs[ss][d0 + 4];
    const float km[8] = {k0v.x,k0v.y,k0v.z,k0v.w,k1v.x,k1v.y,k1v.z,k1v.w};
    const float vd[8] = {v0v.x,v0v.y,v0v.z,v0v.w,v1v.x,v1v.y,v1v.z,v1v.w};
#pragma unroll
    for (int i = 0; i < 8; ++i)
#pragma unroll
      for (int j = 0; j < 8; ++j) acc[i][j] = fmaf(km[i], vd[j], acc[i][j]);
  }
  __syncthreads();
  float (*kvm)[68] = (float(*)[68])&kp[0][0];
  if (h2 == 0) {
#pragma unroll
    for (int i = 0; i < 8; ++i)
#pragma unroll
      for (int j = 0; j < 8; ++j) kvm[m0 + i][d0 + j] = acc[i][j];
  }
  __syncthreads();
  if (h2 == 1) {
#pragma unroll
    for (int i = 0; i < 8; ++i)
#pragma unroll
      for (int j = 0; j < 8; ++j) kvm[m0 + i][d0 + j] += acc[i][j];
  }
  __syncthreads();
  float* kvb = kv + ((size_t)bh << 13);
#pragma unroll
  for (int it = 0; it < 8; ++it) {
    const int idx = (it << 10) + (tid << 2);
    const int m = idx >> 6, d = idx & 63;
    atomicAdd(&kvb[idx + 0], kvm[m][d + 0]);
    atomicAdd(&kvb[idx + 1], kvm[m][d + 1]);
    atomicAdd(&kvb[idx + 2], kvm[m][d + 2]);
    atomicAdd(&kvb[idx + 3], kvm[m][d + 3]);
  }
}

// ---------------------------------------------------------------------------
// Kernel C: qkv[t][d] = sum_m q_prime[t][m]*kv[m][d].  kv column in 128 VGPRs
// (lane = d), q_prime rows wave-uniform -> scalar loads -> pure FMA loop.
// grid 256 = 16 bh * 16 t-tiles(64), block 256 (4 waves * 16 t each).
// ---------------------------------------------------------------------------
__global__ __launch_bounds__(256) void qkv_kernel(
    const float* __restrict__ qp, const float* __restrict__ kv,
    float* __restrict__ qkvb)
{
  const int bid = blockIdx.x;
  const int bh = bid >> 4, tt = bid & 15;
  const int tid = threadIdx.x;
  const int w = __builtin_amdgcn_readfirstlane(tid >> 6);
  const int lane = tid & 63;

  const float* kvb = kv + ((size_t)bh << 13);
  float kvr[128];
#pragma unroll
  for (int m = 0; m < 128; ++m) kvr[m] = kvb[(m << 6) + lane];

  const int tbase = (tt << 6) + (w << 4);
  const float* qrow = qp + (((size_t)bh * TT + tbase) << 7);
  float* ob = qkvb + (((size_t)bh * TT + tbase) << 6);
  for (int t = 0; t < 16; ++t) {
    const float* qr = qrow + (t << 7);
    float acc = 0.f;
#pragma unroll
    for (int m = 0; m < 128; ++m) acc = fmaf(qr[m], kvr[m], acc);
    ob[(t << 6) + lane] = acc;
  }
}

// ---------------------------------------------------------------------------
// Kernel D: banded local attention + log-space combine + output.
// grid 512 = 16 bh * 32 tiles(32 queries), block 256.  ~152 KB LDS.
// ---------------------------------------------------------------------------
__global__ __launch_bounds__(256) void band_kernel(
    const float* __restrict__ Q, const float* __restrict__ K,
    const float* __restrict__ V,
    const float* __restrict__ qp, const float* __restrict__ kp,
    const float* __restrict__ qkvb, const float* __restrict__ ksum,
    const float* __restrict__ qstab, const unsigned int* __restrict__ kmax,
    float* __restrict__ out)
{
  __shared__ __align__(16) float q_s[32][68];
  __shared__ __align__(16) float qp_s[32][132];
  __shared__ __align__(16) float kpw[96][132];
  __shared__ __align__(16) float vw[96][68];
  __shared__ __align__(16) float QKr[32 * 100];
  __shared__ __align__(16) float dpr[32 * 100];
  __shared__ __align__(16) float un1[96 * 68];   // k-window, later dotsT[96][36]
  __shared__ float pls_s[32], ln_s[32], ps_s[32];
  __shared__ float ksum_s[128];

  const int bid = blockIdx.x;
  const int bh = bid >> 5, tile = bid & 31;
  const int b = bh >> 3, h = bh & 7;
  const int t0 = tile << 5;
  const int k0 = t0 - 32;
  const int tid = threadIdx.x;
  const float kstab = __logf(__uint_as_float(kmax[bh]));

  // ---- stage ----
  {
    const int idx = tid << 3;
    const int r = idx >> 6, c = idx & 63;
    const float* src = Q + ((((size_t)b * TT + t0 + r) * HH + h) << 6) + c;
    *(float4*)&q_s[r][c]     = *(const float4*)src;
    *(float4*)&q_s[r][c + 4] = *(const float4*)(src + 4);
  }
#pragma unroll
  for (int it = 0; it < 4; ++it) {
    const int idx = (it << 10) + (tid << 2);
    const int r = idx >> 7, c = idx & 127;
    *(float4*)&qp_s[r][c] = *(const float4*)&qp[(((size_t)bh * TT + t0 + r) << 7) + c];
  }
  float (*kw)[68] = (float(*)[68])un1;
#pragma unroll
  for (int it = 0; it < 6; ++it) {
    const int idx = (it << 10) + (tid << 2);
    const int r = idx >> 6, c = idx & 63;
    const int tg = min(max(k0 + r, 0), TT - 1);
    *(float4*)&kw[r][c] = *(const float4*)(K + ((((size_t)b * TT + tg) * HH + h) << 6) + c);
  }
#pragma unroll
  for (int it = 0; it < 12; ++it) {
    const int idx = (it << 10) + (tid << 2);
    const int r = idx >> 7, c = idx & 127;
    const int tg = min(max(k0 + r, 0), TT - 1);
    *(float4*)&kpw[r][c] = *(const float4*)&kp[(((size_t)bh * TT + tg) << 7) + c];
  }
#pragma unroll
  for (int it = 0; it < 6; ++it) {
    const int idx = (it << 10) + (tid << 2);
    const int r = idx >> 6, c = idx & 63;
    const int tg = min(max(k0 + r, 0), TT - 1);
    *(float4*)&vw[r][c] = *(const float4*)(V + ((((size_t)b * TT + tg) * HH + h) << 6) + c);
  }
  if (tid < 128) ksum_s[tid] = ksum[(bh << 7) + tid];
  if (tid >= 128 && tid < 160) {
    const int r = tid - 128;
    pls_s[r] = qstab[(size_t)bh * TT + t0 + r] + kstab;
  }
  __syncthreads();

  const int tq = (tid >> 5) << 2;      // query sub-row base (8 groups * 4)
  const int r0 = (tid & 31) * 3;       // key-window row base (32 groups * 3)

  // ---- P1: QK rect (32 x 96 x 64) ----
  {
    float acc[4][3];
#pragma unroll
    for (int i = 0; i < 4; ++i)
#pragma unroll
      for (int j = 0; j < 3; ++j) acc[i][j] = 0.f;
#pragma unroll
    for (int cc = 0; cc < 16; ++cc) {
      float qv[4][4], kvv[3][4];
#pragma unroll
      for (int i = 0; i < 4; ++i) {
        const float4 v4 = *(const float4*)&q_s[tq + i][cc << 2];
        qv[i][0] = v4.x; qv[i][1] = v4.y; qv[i][2] = v4.z; qv[i][3] = v4.w;
      }
#pragma unroll
      for (int j = 0; j < 3; ++j) {
        const float4 v4 = *(const float4*)&kw[r0 + j][cc << 2];
        kvv[j][0] = v4.x; kvv[j][1] = v4.y; kvv[j][2] = v4.z; kvv[j][3] = v4.w;
      }
#pragma unroll
      for (int i = 0; i < 4; ++i)
#pragma unroll
        for (int j = 0; j < 3; ++j)
#pragma unroll
          for (int u = 0; u < 4; ++u)
            acc[i][j] = fmaf(qv[i][u], kvv[j][u], acc[i][j]);
    }
#pragma unroll
    for (int i = 0; i < 4; ++i)
#pragma unroll
      for (int j = 0; j < 3; ++j) {
        const int r = r0 + j;
        const int gk = k0 + r;
        QKr[(tq + i) * 100 + r] = (gk >= 0 && gk < TT) ? TEMP * acc[i][j] : NEGINF;
      }
  }
  // ---- P2: dots_prime rect (32 x 96 x 128) ----
  {
    float acc[4][3];
#pragma unroll
    for (int i = 0; i < 4; ++i)
#pragma unroll
      for (int j = 0; j < 3; ++j) acc[i][j] = 0.f;
#pragma unroll
    for (int cc = 0; cc < 32; ++cc) {
      float qv[4][4], kvv[3][4];
#pragma unroll
      for (int i = 0; i < 4; ++i) {
        const float4 v4 = *(const float4*)&qp_s[tq + i][cc << 2];
        qv[i][0] = v4.x; qv[i][1] = v4.y; qv[i][2] = v4.z; qv[i][3] = v4.w;
      }
#pragma unroll
      for (int j = 0; j < 3; ++j) {
        const float4 v4 = *(const float4*)&kpw[r0 + j][cc << 2];
        kvv[j][0] = v4.x; kvv[j][1] = v4.y; kvv[j][2] = v4.z; kvv[j][3] = v4.w;
      }
#pragma unroll
      for (int i = 0; i < 4; ++i)
#pragma unroll
        for (int j = 0; j < 3; ++j)
#pragma unroll
          for (int u = 0; u < 4; ++u)
            acc[i][j] = fmaf(qv[i][u], kvv[j][u], acc[i][j]);
    }
#pragma unroll
    for (int i = 0; i < 4; ++i)
#pragma unroll
      for (int j = 0; j < 3; ++j) {
        const int r = r0 + j;
        const int gk = k0 + r;
        dpr[(tq + i) * 100 + r] = (gk >= 0 && gk < TT) ? acc[i][j] : 0.f;
      }
  }
  __syncthreads();

  // ---- P3: per-row reductions + log-space norm ----
  {
    const int t = tid >> 3, sub = tid & 7;
    float mx = -3e30f;
    for (int j = sub; j < 64; j += 8) mx = fmaxf(mx, QKr[t * 100 + t + j]);
    mx = fmaxf(mx, __shfl_xor(mx, 1));
    mx = fmaxf(mx, __shfl_xor(mx, 2));
    mx = fmaxf(mx, __shfl_xor(mx, 4));
    float se = 0.f, dps = 0.f;
    for (int j = sub; j < 64; j += 8) {
      se  += __expf(QKr[t * 100 + t + j] - mx);
      dps += dpr[t * 100 + t + j];
    }
    float qk1 = 0.f;
    for (int m = sub; m < 128; m += 8) qk1 += qp_s[t][m] * ksum_s[m];
    se  += __shfl_xor(se, 1);  se  += __shfl_xor(se, 2);  se  += __shfl_xor(se, 4);
    dps += __shfl_xor(dps, 1); dps += __shfl_xor(dps, 2); dps += __shfl_xor(dps, 4);
    qk1 += __shfl_xor(qk1, 1); qk1 += __shfl_xor(qk1, 2); qk1 += __shfl_xor(qk1, 4);
    if (sub == 0) {
      const float lse = mx + __logf(se);
      const float lr  = fmaxf(qk1 - dps, 1e-24f);
      const float lrl = __logf(lr) + pls_s[t];
      const float a = fmaxf(lse, lrl), bmn = fminf(lse, lrl);
      const float ln = a + log1pf(__expf(bmn - a));
      ln_s[t] = ln;
      ps_s[t] = __expf(pls_s[t] - ln);
    }
  }
  __syncthreads();

  // ---- P4: dots -> transposed (overwrites k-window) ----
  float (*dT)[36] = (float(*)[36])un1;
#pragma unroll
  for (int i = 0; i < 12; ++i) {
    const int p = (i << 8) + tid;
    const int r = p >> 5, t = p & 31;
    const int j = r - t;
    float d = 0.f;
    if (j >= 0 && j < 64)
      d = __expf(QKr[t * 100 + r] - ln_s[t]) - dpr[t * 100 + r] * ps_s[t];
    dT[r][t] = d;
  }
  __syncthreads();

  // ---- P5: out_local GEMM (32 x 64 x 96) + epilogue ----
  {
    const int rq = tid >> 6;
    const int tq5 = ((tid >> 3) & 7) << 2;
    const int d0 = (tid & 7) << 3;
    float acc[4][8];
#pragma unroll
    for (int i = 0; i < 4; ++i)
#pragma unroll
      for (int j = 0; j < 8; ++j) acc[i][j] = 0.f;
    const int rbase = rq * 24;
    for (int rr = 0; rr < 24; ++rr) {
      const int r = rbase + rr;
      const float4 dv = *(const float4*)&dT[r][tq5];
      const float4 v0 = *(const float4*)&vw[r][d0];
      const float4 v1 = *(const float4*)&vw[r][d0 + 4];
      const float dvv[4] = {dv.x, dv.y, dv.z, dv.w};
      const float vv8[8] = {v0.x,v0.y,v0.z,v0.w,v1.x,v1.y,v1.z,v1.w};
#pragma unroll
      for (int i = 0; i < 4; ++i)
#pragma unroll
        for (int j = 0; j < 8; ++j) acc[i][j] = fmaf(dvv[i], vv8[j], acc[i][j]);
    }
    float* mg = QKr;   // reuse as merge buffer [32][68]
#pragma unroll
    for (int i2 = 0; i2 < 8; ++i2) {
      const int p = (i2 << 8) + tid;
      mg[(p >> 6) * 68 + (p & 63)] = 0.f;
    }
    __syncthreads();
#pragma unroll
    for (int i = 0; i < 4; ++i)
#pragma unroll
      for (int j = 0; j < 8; ++j)
        atomicAdd(&mg[(tq5 + i) * 68 + d0 + j], acc[i][j]);
    __syncthreads();

    const int t = tid >> 3, dd = (tid & 7) << 3;
    const int tg = t0 + t;
    const float ps = ps_s[t];
    const float* qk_r = qkvb + (((size_t)bh * TT + tg) << 6) + dd;
    float4 a0 = *(float4*)&mg[t * 68 + dd];
    float4 a1 = *(float4*)&mg[t * 68 + dd + 4];
    const float4 q0 = *(const float4*)qk_r;
    const float4 q1 = *(const float4*)(qk_r + 4);
    a0.x = fmaf(q0.x, ps, a0.x); a0.y = fmaf(q0.y, ps, a0.y);
    a0.z = fmaf(q0.z, ps, a0.z); a0.w = fmaf(q0.w, ps, a0.w);
    a1.x = fmaf(q1.x, ps, a1.x); a1.y = fmaf(q1.y, ps, a1.y);
    a1.z = fmaf(q1.z, ps, a1.z); a1.w = fmaf(q1.w, ps, a1.w);
    float* ob = out + ((((size_t)b * TT + tg) * HH + h) << 6) + dd;
    *(float4*)ob = a0;
    *(float4*)(ob + 4) = a1;
  }
}

extern "C" void kernel_launch(void* const* d_in, const int* in_sizes, int n_in,
                              void* d_out, int out_size, void* d_ws, size_t ws_size,
                              hipStream_t stream) {
  (void)in_sizes; (void)n_in; (void)out_size; (void)ws_size;
  const float* Q    = (const float*)d_in[0];
  const float* K    = (const float*)d_in[1];
  const float* V    = (const float*)d_in[2];
  const float* proj = (const float*)d_in[3];
  float* out = (float*)d_out;
  char* ws = (char*)d_ws;

  float*        qp    = (float*)(ws + OFF_QP);
  float*        kf    = (float*)(ws + OFF_KF);
  float*        qkvb  = (float*)(ws + OFF_QKV);
  float*        kv    = (float*)(ws + OFF_KV);
  float*        ksum  = (float*)(ws + OFF_KSUM);
  unsigned int* kmax  = (unsigned int*)(ws + OFF_KMAX);
  float*        qstab = (float*)(ws + OFF_QSTAB);

  hipMemsetAsync(ws + OFF_KV, 0, ZERO_SZ, stream);
  feat_kernel<<<256, 256, 0, stream>>>(Q, K, proj, qp, kf, qstab, kmax);
  kv_kernel<<<128, 256, 0, stream>>>(V, kf, kmax, kv, ksum);
  qkv_kernel<<<256, 256, 0, stream>>>(qp, kv, qkvb);
  band_kernel<<<512, 256, 0, stream>>>(Q, K, V, qp, kf, qkvb, ksum, qstab, kmax, out);
}

// Round 2
// 152.708 us; speedup vs baseline: 1.6227x; 1.6227x over previous
//
#include <hip/hip_runtime.h>

#define TT 1024
#define HH 8
#define EE 64
#define MM 128
#define NBH 16

#define NORMALIZER 0.35355339059327379f
#define RSQRT_M    0.08838834764831845f
#define TEMP       0.125f
#define NEGINF     -1e24f

// ws byte offsets
#define OFF_QP    0u            // [BH][T][M] f32  8 MB   q_prime
#define OFF_KF    8388608u      // [BH][T][M] f32  8 MB   exp(logfeat_k) -> k_prime (in place)
#define OFF_QKV   16777216u     // [BH][T][E] f32  4 MB
#define OFF_KV    20971520u     // [BH][M][E] f32  512 KB
#define OFF_KSUM  21495808u     // [BH][M]    f32  8 KB
#define OFF_KMAX  21504000u     // [BH]       u32  64 B
#define OFF_QSTAB 21504064u     // [BH][T]    f32  64 KB
#define ZERO_SZ   (524288u + 8192u + 64u)   // kv + ksum + kmax

// ---------------------------------------------------------------------------
// Kernel A: FAVOR+ features. Grid 512 = 2 paths * 16 bh * 16 rowtiles(64).
// Stage x transposed in LDS (coalesced loads, conflict-free reads), lane=row,
// proj rows wave-uniform -> scalar loads. 17 KB LDS.
// ---------------------------------------------------------------------------
__global__ __launch_bounds__(256, 2) void feat_kernel(
    const float* __restrict__ Q, const float* __restrict__ K,
    const float* __restrict__ proj,
    float* __restrict__ qp, float* __restrict__ kf,
    float* __restrict__ qstab, unsigned int* __restrict__ kmax)
{
  __shared__ float xsT[64][65];   // [e][row]
  __shared__ float Mh[64][4];

  const int bid  = blockIdx.x;
  const int path = bid >> 8;          // 0=q, 1=k
  const int bh   = (bid >> 4) & 15;
  const int rt   = bid & 15;
  const int b = bh >> 3, h = bh & 7;
  const int t0 = rt << 6;
  const int tid = threadIdx.x;

  const float* x = path ? K : Q;
  const float* xbase = x + (((size_t)b * TT * HH + h) << 6);
#pragma unroll
  for (int it = 0; it < 4; ++it) {
    const int idx = (it << 8) + tid;
    const int r = idx >> 4, c = (idx & 15) << 2;
    const float4 f4 = *(const float4*)&xbase[(size_t)(t0 + r) * 512 + c];
    xsT[c + 0][r] = f4.x; xsT[c + 1][r] = f4.y;
    xsT[c + 2][r] = f4.z; xsT[c + 3][r] = f4.w;
  }
  __syncthreads();

  const int lane = tid & 63;
  const int w = __builtin_amdgcn_readfirstlane(tid >> 6);
  float xv[64];
  float diag = 0.f;
#pragma unroll
  for (int c = 0; c < 64; ++c) { xv[c] = xsT[c][lane]; diag = fmaf(xv[c], xv[c], diag); }
  diag *= 0.0625f;   // 0.5*temp

  float lf[32];
  float mx = -3e30f;
  const int mbase = w << 5;
  for (int mm = 0; mm < 32; ++mm) {
    const float* pr = proj + ((mbase + mm) << 6);
    float a0 = 0.f, a1 = 0.f;
#pragma unroll
    for (int c = 0; c < 64; c += 2) {
      a0 = fmaf(xv[c], pr[c], a0);
      a1 = fmaf(xv[c + 1], pr[c + 1], a1);
    }
    const float v = fmaf(NORMALIZER, a0 + a1, -diag);
    lf[mm] = v;
    mx = fmaxf(mx, v);
  }
  Mh[lane][w] = mx;
  __syncthreads();
  const float m0 = fmaxf(fmaxf(Mh[lane][0], Mh[lane][1]), fmaxf(Mh[lane][2], Mh[lane][3]));

  float ov[32];
  if (path == 0) {
#pragma unroll
    for (int mm = 0; mm < 32; ++mm) ov[mm] = RSQRT_M * __expf(lf[mm] - m0);
    if (w == 0) qstab[(size_t)bh * TT + t0 + lane] = m0;
  } else {
#pragma unroll
    for (int mm = 0; mm < 32; ++mm) ov[mm] = __expf(lf[mm]);
    if (w == 0) {
      float bm = m0;
#pragma unroll
      for (int off = 1; off < 64; off <<= 1) bm = fmaxf(bm, __shfl_xor(bm, off));
      if (lane == 0) atomicMax(kmax + bh, __float_as_uint(__expf(bm)));
    }
  }
  float* dst = (path ? kf : qp) + (((size_t)bh * TT + t0 + lane) << 7) + mbase;
#pragma unroll
  for (int q4 = 0; q4 < 8; ++q4)
    *(float4*)&dst[q4 << 2] =
        make_float4(ov[q4 * 4], ov[q4 * 4 + 1], ov[q4 * 4 + 2], ov[q4 * 4 + 3]);
}

// ---------------------------------------------------------------------------
// Kernel B: k_prime scale (in place), ksum, kv accumulation.
// Grid 256 = 16 bh * 16 s-tiles(64). 51 KB LDS.
// ---------------------------------------------------------------------------
__global__ __launch_bounds__(256, 2) void kv_kernel(
    const float* __restrict__ V, float* __restrict__ kf,
    const unsigned int* __restrict__ kmax,
    float* __restrict__ kv, float* __restrict__ ksum)
{
  __shared__ __align__(16) float smem[64 * 132 + 64 * 68];
  float (*kp_s)[132] = (float(*)[132])smem;
  float (*vs)[68] = (float(*)[68])(smem + 64 * 132);

  const int bid = blockIdx.x;
  const int bh = bid >> 4, st = bid & 15;
  const int b = bh >> 3, h = bh & 7;
  const int tid = threadIdx.x;
  const float scale = RSQRT_M / __uint_as_float(kmax[bh]);
  const size_t base_kf = ((size_t)bh * TT + ((size_t)st << 6)) << 7;

#pragma unroll
  for (int it = 0; it < 8; ++it) {
    const int idx = (it << 10) + (tid << 2);   // 64*128
    const int r = idx >> 7, c = idx & 127;
    float4 vv = *(const float4*)&kf[base_kf + idx];
    vv.x *= scale; vv.y *= scale; vv.z *= scale; vv.w *= scale;
    *(float4*)&kp_s[r][c] = vv;
    *(float4*)&kf[base_kf + idx] = vv;  // write back k_prime
  }
#pragma unroll
  for (int it = 0; it < 4; ++it) {
    const int idx = (it << 10) + (tid << 2);   // 64*64
    const int r = idx >> 6, c = idx & 63;
    const int tg = (st << 6) + r;
    *(float4*)&vs[r][c] = *(const float4*)(V + ((((size_t)b * TT + tg) * HH + h) << 6) + c);
  }
  __syncthreads();

  if (tid < 128) {
    float s = 0.f;
    for (int ss = 0; ss < 64; ++ss) s += kp_s[ss][tid];
    atomicAdd(&ksum[(bh << 7) + tid], s);
  }

  const int h2 = tid >> 7;                 // s half
  const int m0 = ((tid & 127) >> 3) << 3;  // 16 tiles of 8 m
  const int d0 = (tid & 7) << 3;           // 8 tiles of 8 d
  float acc[8][8];
#pragma unroll
  for (int i = 0; i < 8; ++i)
#pragma unroll
    for (int j = 0; j < 8; ++j) acc[i][j] = 0.f;

  const int s0 = h2 << 5;
  for (int ss = s0; ss < s0 + 32; ++ss) {
    const float4 k0v = *(const float4*)&kp_s[ss][m0];
    const float4 k1v = *(const float4*)&kp_s[ss][m0 + 4];
    const float4 v0v = *(const float4*)&vs[ss][d0];
    const float4 v1v = *(const float4*)&vs[ss][d0 + 4];
    const float km[8] = {k0v.x,k0v.y,k0v.z,k0v.w,k1v.x,k1v.y,k1v.z,k1v.w};
    const float vd[8] = {v0v.x,v0v.y,v0v.z,v0v.w,v1v.x,v1v.y,v1v.z,v1v.w};
#pragma unroll
    for (int i = 0; i < 8; ++i)
#pragma unroll
      for (int j = 0; j < 8; ++j) acc[i][j] = fmaf(km[i], vd[j], acc[i][j]);
  }
  __syncthreads();
  float (*kvm)[68] = (float(*)[68])smem;   // 128x68 fits in 64*132+64*68
  if (h2 == 0) {
#pragma unroll
    for (int i = 0; i < 8; ++i)
#pragma unroll
      for (int j = 0; j < 8; ++j) kvm[m0 + i][d0 + j] = acc[i][j];
  }
  __syncthreads();
  if (h2 == 1) {
#pragma unroll
    for (int i = 0; i < 8; ++i)
#pragma unroll
      for (int j = 0; j < 8; ++j) kvm[m0 + i][d0 + j] += acc[i][j];
  }
  __syncthreads();
  float* kvb = kv + ((size_t)bh << 13);
#pragma unroll
  for (int it = 0; it < 8; ++it) {
    const int idx = (it << 10) + (tid << 2);
    const int m = idx >> 6, d = idx & 63;
    atomicAdd(&kvb[idx + 0], kvm[m][d + 0]);
    atomicAdd(&kvb[idx + 1], kvm[m][d + 1]);
    atomicAdd(&kvb[idx + 2], kvm[m][d + 2]);
    atomicAdd(&kvb[idx + 3], kvm[m][d + 3]);
  }
}

// ---------------------------------------------------------------------------
// Kernel C: qkv = q_prime @ kv.  Grid 512 = 16 bh * 32 t-tiles(32).
// kv column in 128 VGPRs (lane=d), 2-row ILP, q_prime via scalar loads.
// ---------------------------------------------------------------------------
__global__ __launch_bounds__(256, 2) void qkv_kernel(
    const float* __restrict__ qp, const float* __restrict__ kv,
    float* __restrict__ qkvb)
{
  const int bid = blockIdx.x;
  const int bh = bid >> 5, tt = bid & 31;
  const int tid = threadIdx.x;
  const int w = __builtin_amdgcn_readfirstlane(tid >> 6);
  const int lane = tid & 63;

  const float* kvb = kv + ((size_t)bh << 13);
  float kvr[128];
#pragma unroll
  for (int m = 0; m < 128; ++m) kvr[m] = kvb[(m << 6) + lane];

  const int tbase = (tt << 5) + (w << 3);
  const float* qrow = qp + (((size_t)bh * TT + tbase) << 7);
  float* ob = qkvb + (((size_t)bh * TT + tbase) << 6);
#pragma unroll
  for (int tp = 0; tp < 4; ++tp) {
    const float* q0 = qrow + (tp << 8);
    float a0 = 0.f, a1 = 0.f;
#pragma unroll
    for (int m = 0; m < 128; ++m) {
      a0 = fmaf(q0[m], kvr[m], a0);
      a1 = fmaf(q0[128 + m], kvr[m], a1);
    }
    ob[(tp << 7) + lane] = a0;
    ob[(tp << 7) + 64 + lane] = a1;
  }
}

// ---------------------------------------------------------------------------
// Kernel D: banded local attention. Grid 1024 = 16 bh * 64 tiles(16 queries),
// XCD-chunk swizzled. ~32 KB LDS, 4 blocks/CU. Band rects held in registers,
// 16-lane shuffle reductions, dots materialized as transposed 80x16 tile.
// ---------------------------------------------------------------------------
__global__ __launch_bounds__(256, 4) void band_kernel(
    const float* __restrict__ Q, const float* __restrict__ K,
    const float* __restrict__ V,
    const float* __restrict__ qp, const float* __restrict__ kp,
    const float* __restrict__ qkvb, const float* __restrict__ ksum,
    const float* __restrict__ qstab, const unsigned int* __restrict__ kmax,
    float* __restrict__ out)
{
  __shared__ __align__(16) float bufA[16][68];   // q / qp chunks
  __shared__ __align__(16) float bufB[80][68];   // k / kp chunks / v
  __shared__ float dT[80 * 17];                  // dots transposed [r][t]
  __shared__ float ksum_s[128];
  __shared__ float pls_s[16];
  __shared__ float psb[16];

  const int g = blockIdx.x;
  const int lg = ((g & 7) << 7) | (g >> 3);      // XCD chunk swizzle (1024 wgs)
  const int bh = lg >> 6, tile = lg & 63;
  const int b = bh >> 3, h = bh & 7;
  const int t0 = tile << 4;
  const int k0 = t0 - 32;
  const int tid = threadIdx.x;

  const float* Kbase = K + (((size_t)b * TT * HH + h) << 6);
  const float* Vbase = V + (((size_t)b * TT * HH + h) << 6);
  const float* Qbase = Q + (((size_t)b * TT * HH + h) << 6);
  const float* kpb = kp + (((size_t)bh * TT) << 7);
  const float* qpb = qp + (((size_t)bh * TT) << 7);

  // ---- initial staging: q->A, k->B, ksum, pls ----
  {
    const int r = tid >> 4, c4 = (tid & 15) << 2;
    *(float4*)&bufA[r][c4] = *(const float4*)&Qbase[(size_t)(t0 + r) * 512 + c4];
  }
#pragma unroll
  for (int it = 0; it < 5; ++it) {
    const int idx = (it << 8) + tid;
    const int r = idx >> 4, c4 = (idx & 15) << 2;
    const int tg = min(max(k0 + r, 0), TT - 1);
    *(float4*)&bufB[r][c4] = *(const float4*)&Kbase[(size_t)tg * 512 + c4];
  }
  if (tid < 128) ksum_s[tid] = ksum[(bh << 7) + tid];
  if (tid >= 128 && tid < 144) {
    const int r = tid - 128;
    pls_s[r] = qstab[(size_t)bh * TT + t0 + r] + __logf(__uint_as_float(kmax[bh]));
  }
  __syncthreads();

  const int tq = tid >> 4;            // query row 0..15
  const int r0 = (tid & 15) * 5;      // key rows r0..r0+4

  // ---- GEMM1: QK (16 x 80 x 64) ----
  float acc1[5] = {0.f, 0.f, 0.f, 0.f, 0.f};
#pragma unroll
  for (int cc = 0; cc < 16; ++cc) {
    const float4 a4 = *(const float4*)&bufA[tq][cc << 2];
#pragma unroll
    for (int i = 0; i < 5; ++i) {
      const float4 b4 = *(const float4*)&bufB[r0 + i][cc << 2];
      acc1[i] = fmaf(a4.x, b4.x, acc1[i]);
      acc1[i] = fmaf(a4.y, b4.y, acc1[i]);
      acc1[i] = fmaf(a4.z, b4.z, acc1[i]);
      acc1[i] = fmaf(a4.w, b4.w, acc1[i]);
    }
  }
  __syncthreads();

  // ---- GEMM2: dots_prime (16 x 80 x 128), two 64-col chunks ----
  float acc2[5] = {0.f, 0.f, 0.f, 0.f, 0.f};
#pragma unroll 1
  for (int ch = 0; ch < 2; ++ch) {
    const int co = ch << 6;
    {
      const int r = tid >> 4, c4 = (tid & 15) << 2;
      *(float4*)&bufA[r][c4] = *(const float4*)&qpb[((size_t)(t0 + r) << 7) + co + c4];
    }
#pragma unroll
    for (int it = 0; it < 5; ++it) {
      const int idx = (it << 8) + tid;
      const int r = idx >> 4, c4 = (idx & 15) << 2;
      const int tg = min(max(k0 + r, 0), TT - 1);
      *(float4*)&bufB[r][c4] = *(const float4*)&kpb[((size_t)tg << 7) + co + c4];
    }
    __syncthreads();
#pragma unroll
    for (int cc = 0; cc < 16; ++cc) {
      const float4 a4 = *(const float4*)&bufA[tq][cc << 2];
#pragma unroll
      for (int i = 0; i < 5; ++i) {
        const float4 b4 = *(const float4*)&bufB[r0 + i][cc << 2];
        acc2[i] = fmaf(a4.x, b4.x, acc2[i]);
        acc2[i] = fmaf(a4.y, b4.y, acc2[i]);
        acc2[i] = fmaf(a4.z, b4.z, acc2[i]);
        acc2[i] = fmaf(a4.w, b4.w, acc2[i]);
      }
    }
    __syncthreads();
  }

  // ---- stage v->B (writes are after the barrier above) ----
#pragma unroll
  for (int it = 0; it < 5; ++it) {
    const int idx = (it << 8) + tid;
    const int r = idx >> 4, c4 = (idx & 15) << 2;
    const int tg = min(max(k0 + r, 0), TT - 1);
    *(float4*)&bufB[r][c4] = *(const float4*)&Vbase[(size_t)tg * 512 + c4];
  }

  // ---- P3: in-register masking + reductions + log-space norm + dots ----
  {
    float qkt[5], dpt[5];
#pragma unroll
    for (int i = 0; i < 5; ++i) {
      const int r = r0 + i;
      const int j = r - tq;
      const int gk = k0 + r;
      const bool valid = (j >= 0) && (j < 64) && (gk >= 0) && (gk < TT);
      qkt[i] = valid ? TEMP * acc1[i] : NEGINF;
      dpt[i] = valid ? acc2[i] : 0.f;
    }
    float mx = qkt[0];
#pragma unroll
    for (int i = 1; i < 5; ++i) mx = fmaxf(mx, qkt[i]);
    mx = fmaxf(mx, __shfl_xor(mx, 1));
    mx = fmaxf(mx, __shfl_xor(mx, 2));
    mx = fmaxf(mx, __shfl_xor(mx, 4));
    mx = fmaxf(mx, __shfl_xor(mx, 8));

    float se = 0.f, dps = 0.f;
#pragma unroll
    for (int i = 0; i < 5; ++i) {
      se += __expf(qkt[i] - mx);
      dps += dpt[i];
    }
    float qk1 = 0.f;
    const float* qrow = qpb + ((size_t)(t0 + tq) << 7);
#pragma unroll
    for (int ii = 0; ii < 8; ++ii) {
      const int m = (tid & 15) + (ii << 4);
      qk1 = fmaf(qrow[m], ksum_s[m], qk1);
    }
    se  += __shfl_xor(se, 1);  se  += __shfl_xor(se, 2);
    se  += __shfl_xor(se, 4);  se  += __shfl_xor(se, 8);
    dps += __shfl_xor(dps, 1); dps += __shfl_xor(dps, 2);
    dps += __shfl_xor(dps, 4); dps += __shfl_xor(dps, 8);
    qk1 += __shfl_xor(qk1, 1); qk1 += __shfl_xor(qk1, 2);
    qk1 += __shfl_xor(qk1, 4); qk1 += __shfl_xor(qk1, 8);

    const float pls = pls_s[tq];
    const float lse = mx + __logf(se);
    const float lr = fmaxf(qk1 - dps, 1e-24f);
    const float lrl = __logf(lr) + pls;
    const float aa = fmaxf(lse, lrl), bb = fminf(lse, lrl);
    const float ln = aa + log1pf(__expf(bb - aa));
    const float ps = __expf(pls - ln);
    if ((tid & 15) == 0) psb[tq] = ps;
#pragma unroll
    for (int i = 0; i < 5; ++i) {
      const float d = __expf(qkt[i] - ln) - dpt[i] * ps;
      dT[(r0 + i) * 17 + tq] = d;
    }
  }
  __syncthreads();

  // ---- P5: out_local = dots @ v_win (+ qkv * ps epilogue) ----
  {
    const int t5 = tid >> 4, dg = tid & 15, d0c = dg << 2;
    float a0 = 0.f, a1 = 0.f, a2 = 0.f, a3 = 0.f;
#pragma unroll
    for (int j = 0; j < 64; ++j) {
      const int jj = (j + dg) & 63;     // stagger to spread LDS banks
      const int r = t5 + jj;
      const float dv = dT[r * 17 + t5];
      const float4 v4 = *(const float4*)&bufB[r][d0c];
      a0 = fmaf(dv, v4.x, a0);
      a1 = fmaf(dv, v4.y, a1);
      a2 = fmaf(dv, v4.z, a2);
      a3 = fmaf(dv, v4.w, a3);
    }
    const float ps = psb[t5];
    const float4 q4 = *(const float4*)&qkvb[(((size_t)bh * TT + t0 + t5) << 6) + d0c];
    a0 = fmaf(q4.x, ps, a0);
    a1 = fmaf(q4.y, ps, a1);
    a2 = fmaf(q4.z, ps, a2);
    a3 = fmaf(q4.w, ps, a3);
    float* ob = out + ((((size_t)b * TT + t0 + t5) * HH + h) << 6) + d0c;
    *(float4*)ob = make_float4(a0, a1, a2, a3);
  }
}

extern "C" void kernel_launch(void* const* d_in, const int* in_sizes, int n_in,
                              void* d_out, int out_size, void* d_ws, size_t ws_size,
                              hipStream_t stream) {
  (void)in_sizes; (void)n_in; (void)out_size; (void)ws_size;
  const float* Q    = (const float*)d_in[0];
  const float* K    = (const float*)d_in[1];
  const float* V    = (const float*)d_in[2];
  const float* proj = (const float*)d_in[3];
  float* out = (float*)d_out;
  char* ws = (char*)d_ws;

  float*        qp    = (float*)(ws + OFF_QP);
  float*        kf    = (float*)(ws + OFF_KF);
  float*        qkvb  = (float*)(ws + OFF_QKV);
  float*        kv    = (float*)(ws + OFF_KV);
  float*        ksum  = (float*)(ws + OFF_KSUM);
  unsigned int* kmax  = (unsigned int*)(ws + OFF_KMAX);
  float*        qstab = (float*)(ws + OFF_QSTAB);

  hipMemsetAsync(ws + OFF_KV, 0, ZERO_SZ, stream);
  feat_kernel<<<512, 256, 0, stream>>>(Q, K, proj, qp, kf, qstab, kmax);
  kv_kernel<<<256, 256, 0, stream>>>(V, kf, kmax, kv, ksum);
  qkv_kernel<<<512, 256, 0, stream>>>(qp, kv, qkvb);
  band_kernel<<<1024, 256, 0, stream>>>(Q, K, V, qp, kf, qkvb, ksum, qstab, kmax, out);
}

// Round 3
// 111.295 us; speedup vs baseline: 2.2265x; 1.3721x over previous
//
#include <hip/hip_runtime.h>

#define TT 1024
#define HH 8
#define EE 64
#define MM 128
#define NBH 16

#define NORMALIZER 0.35355339059327379f
#define RSQRT_M    0.08838834764831845f
#define TEMP       0.125f
#define NEGINF     -1e24f

// ws byte offsets
#define OFF_QP    0u            // [BH][T][M] f32  8 MB   q_prime (scaled)
#define OFF_KF    8388608u      // [BH][T][M] f32  8 MB   exp(logfeat_k) RAW
#define OFF_QKV   16777216u     // [BH][T][E] f32  4 MB   (kernel C output)
#define OFF_KVP   16777216u     // [BH][8][M][E] f32 4 MB (overlay: dead before C)
#define OFF_KV    20971520u     // [BH][M][E] f32  512 KB (scaled)
#define OFF_KSUM  21495808u     // [BH][M]    f32  8 KB   (scaled)
#define OFF_KMAX  21504000u     // [BH]       u32  64 B
#define OFF_QSTAB 21504064u     // [BH][T]    f32  64 KB
#define OFF_KSUMP 21569600u     // [BH][8][M] f32  64 KB  (unscaled partials)

// ---------------------------------------------------------------------------
// Kernel A: FAVOR+ features. Grid 512 = 2 paths * 16 bh * 16 rowtiles(64).
// ---------------------------------------------------------------------------
__global__ __launch_bounds__(256, 2) void feat_kernel(
    const float* __restrict__ Q, const float* __restrict__ K,
    const float* __restrict__ proj,
    float* __restrict__ qp, float* __restrict__ kf,
    float* __restrict__ qstab, unsigned int* __restrict__ kmax)
{
  __shared__ float xsT[64][65];   // [e][row]
  __shared__ float Mh[64][4];

  const int bid  = blockIdx.x;
  const int path = bid >> 8;          // 0=q, 1=k
  const int bh   = (bid >> 4) & 15;
  const int rt   = bid & 15;
  const int b = bh >> 3, h = bh & 7;
  const int t0 = rt << 6;
  const int tid = threadIdx.x;

  const float* x = path ? K : Q;
  const float* xbase = x + (((size_t)b * TT * HH + h) << 6);
#pragma unroll
  for (int it = 0; it < 4; ++it) {
    const int idx = (it << 8) + tid;
    const int r = idx >> 4, c = (idx & 15) << 2;
    const float4 f4 = *(const float4*)&xbase[(size_t)(t0 + r) * 512 + c];
    xsT[c + 0][r] = f4.x; xsT[c + 1][r] = f4.y;
    xsT[c + 2][r] = f4.z; xsT[c + 3][r] = f4.w;
  }
  __syncthreads();

  const int lane = tid & 63;
  const int w = __builtin_amdgcn_readfirstlane(tid >> 6);
  float xv[64];
  float diag = 0.f;
#pragma unroll
  for (int c = 0; c < 64; ++c) { xv[c] = xsT[c][lane]; diag = fmaf(xv[c], xv[c], diag); }
  diag *= 0.0625f;   // 0.5*temp

  float lf[32];
  float mx = -3e30f;
  const int mbase = w << 5;
  for (int mm = 0; mm < 32; ++mm) {
    const float* pr = proj + ((mbase + mm) << 6);
    float a0 = 0.f, a1 = 0.f;
#pragma unroll
    for (int c = 0; c < 64; c += 2) {
      a0 = fmaf(xv[c], pr[c], a0);
      a1 = fmaf(xv[c + 1], pr[c + 1], a1);
    }
    const float v = fmaf(NORMALIZER, a0 + a1, -diag);
    lf[mm] = v;
    mx = fmaxf(mx, v);
  }
  Mh[lane][w] = mx;
  __syncthreads();
  const float m0 = fmaxf(fmaxf(Mh[lane][0], Mh[lane][1]), fmaxf(Mh[lane][2], Mh[lane][3]));

  float ov[32];
  if (path == 0) {
#pragma unroll
    for (int mm = 0; mm < 32; ++mm) ov[mm] = RSQRT_M * __expf(lf[mm] - m0);
    if (w == 0) qstab[(size_t)bh * TT + t0 + lane] = m0;
  } else {
#pragma unroll
    for (int mm = 0; mm < 32; ++mm) ov[mm] = __expf(lf[mm]);
    if (w == 0) {
      float bm = m0;
#pragma unroll
      for (int off = 1; off < 64; off <<= 1) bm = fmaxf(bm, __shfl_xor(bm, off));
      if (lane == 0) atomicMax(kmax + bh, __float_as_uint(__expf(bm)));
    }
  }
  float* dst = (path ? kf : qp) + (((size_t)bh * TT + t0 + lane) << 7) + mbase;
#pragma unroll
  for (int q4 = 0; q4 < 8; ++q4)
    *(float4*)&dst[q4 << 2] =
        make_float4(ov[q4 * 4], ov[q4 * 4 + 1], ov[q4 * 4 + 2], ov[q4 * 4 + 3]);
}

// ---------------------------------------------------------------------------
// Kernel B: UNSCALED partial kv + ksum per 128-row s-tile. No atomics, no
// kf write-back. Grid 128 = 16 bh * 8 tiles. Two 64-row LDS chunks, 50 KB.
// ---------------------------------------------------------------------------
__global__ __launch_bounds__(256, 2) void kv_partial(
    const float* __restrict__ V, const float* __restrict__ kf,
    float* __restrict__ kvp, float* __restrict__ ksump)
{
  __shared__ __align__(16) float smem[64 * 132 + 64 * 68];
  float (*kp_s)[132] = (float(*)[132])smem;
  float (*vs)[68] = (float(*)[68])(smem + 64 * 132);

  const int bid = blockIdx.x;
  const int bh = bid >> 3, st = bid & 7;
  const int b = bh >> 3, h = bh & 7;
  const int tid = threadIdx.x;

  const int h2 = tid >> 7;                 // s half within chunk
  const int m0 = ((tid & 127) >> 3) << 3;  // 16 tiles of 8 m
  const int d0 = (tid & 7) << 3;           // 8 tiles of 8 d
  float acc[8][8];
#pragma unroll
  for (int i = 0; i < 8; ++i)
#pragma unroll
    for (int j = 0; j < 8; ++j) acc[i][j] = 0.f;
  float csum = 0.f;   // column sum for tid<128

#pragma unroll 1
  for (int ch = 0; ch < 2; ++ch) {
    const int row0 = (st << 7) + (ch << 6);
    const size_t base_kf = ((size_t)bh * TT + row0) << 7;
#pragma unroll
    for (int it = 0; it < 8; ++it) {
      const int idx = (it << 10) + (tid << 2);   // 64*128
      const int r = idx >> 7, c = idx & 127;
      *(float4*)&kp_s[r][c] = *(const float4*)&kf[base_kf + idx];
    }
#pragma unroll
    for (int it = 0; it < 4; ++it) {
      const int idx = (it << 10) + (tid << 2);   // 64*64
      const int r = idx >> 6, c = idx & 63;
      *(float4*)&vs[r][c] = *(const float4*)(V + ((((size_t)b * TT + row0 + r) * HH + h) << 6) + c);
    }
    __syncthreads();

    if (tid < 128) {
      float s = 0.f;
      for (int ss = 0; ss < 64; ++ss) s += kp_s[ss][tid];
      csum += s;
    }
    const int s0 = h2 << 5;
    for (int ss = s0; ss < s0 + 32; ++ss) {
      const float4 k0v = *(const float4*)&kp_s[ss][m0];
      const float4 k1v = *(const float4*)&kp_s[ss][m0 + 4];
      const float4 v0v = *(const float4*)&vs[ss][d0];
      const float4 v1v = *(const float4*)&vs[ss][d0 + 4];
      const float km[8] = {k0v.x,k0v.y,k0v.z,k0v.w,k1v.x,k1v.y,k1v.z,k1v.w};
      const float vd[8] = {v0v.x,v0v.y,v0v.z,v0v.w,v1v.x,v1v.y,v1v.z,v1v.w};
#pragma unroll
      for (int i = 0; i < 8; ++i)
#pragma unroll
        for (int j = 0; j < 8; ++j) acc[i][j] = fmaf(km[i], vd[j], acc[i][j]);
    }
    __syncthreads();
  }

  if (tid < 128) ksump[(bid << 7) + tid] = csum;

  // merge the two s-halves via LDS, then plain stores of the partial
  float (*kvm)[68] = (float(*)[68])smem;   // 128x68 fits
  if (h2 == 0) {
#pragma unroll
    for (int i = 0; i < 8; ++i)
#pragma unroll
      for (int j = 0; j < 8; ++j) kvm[m0 + i][d0 + j] = acc[i][j];
  }
  __syncthreads();
  if (h2 == 1) {
#pragma unroll
    for (int i = 0; i < 8; ++i)
#pragma unroll
      for (int j = 0; j < 8; ++j) kvm[m0 + i][d0 + j] += acc[i][j];
  }
  __syncthreads();
  float* kvb = kvp + ((size_t)bid << 13);
#pragma unroll
  for (int it = 0; it < 8; ++it) {
    const int idx = (it << 10) + (tid << 2);
    const int m = idx >> 6, d = idx & 63;
    *(float4*)&kvb[idx] = make_float4(kvm[m][d], kvm[m][d + 1], kvm[m][d + 2], kvm[m][d + 3]);
  }
}

// ---------------------------------------------------------------------------
// Kernel B2: reduce 8 partials, apply scale = RSQRT_M / kmax.
// Grid 136: blocks 0..127 -> kv (1024 elems each), 128..135 -> ksum.
// ---------------------------------------------------------------------------
__global__ __launch_bounds__(256, 4) void kv_reduce(
    const float* __restrict__ kvp, const float* __restrict__ ksump,
    const unsigned int* __restrict__ kmax,
    float* __restrict__ kv, float* __restrict__ ksum)
{
  const int bid = blockIdx.x;
  const int tid = threadIdx.x;
  if (bid < 128) {
    const int g = (bid << 10) + (tid << 2);
    const int bh = g >> 13, idx = g & 8191;
    const float scale = RSQRT_M / __uint_as_float(kmax[bh]);
    float4 s = make_float4(0.f, 0.f, 0.f, 0.f);
#pragma unroll
    for (int p = 0; p < 8; ++p) {
      const float4 v = *(const float4*)&kvp[(((size_t)bh << 3) + p << 13) + idx];
      s.x += v.x; s.y += v.y; s.z += v.z; s.w += v.w;
    }
    s.x *= scale; s.y *= scale; s.z *= scale; s.w *= scale;
    *(float4*)&kv[((size_t)bh << 13) + idx] = s;
  } else {
    const int g = ((bid - 128) << 8) + tid;
    const int bh = g >> 7, m = g & 127;
    const float scale = RSQRT_M / __uint_as_float(kmax[bh]);
    float s = 0.f;
#pragma unroll
    for (int p = 0; p < 8; ++p) s += ksump[(((bh << 3) + p) << 7) + m];
    ksum[(bh << 7) + m] = s * scale;
  }
}

// ---------------------------------------------------------------------------
// Kernel C: qkv = q_prime @ kv (kv pre-scaled). Grid 512.
// ---------------------------------------------------------------------------
__global__ __launch_bounds__(256, 2) void qkv_kernel(
    const float* __restrict__ qp, const float* __restrict__ kv,
    float* __restrict__ qkvb)
{
  const int bid = blockIdx.x;
  const int bh = bid >> 5, tt = bid & 31;
  const int tid = threadIdx.x;
  const int w = __builtin_amdgcn_readfirstlane(tid >> 6);
  const int lane = tid & 63;

  const float* kvb = kv + ((size_t)bh << 13);
  float kvr[128];
#pragma unroll
  for (int m = 0; m < 128; ++m) kvr[m] = kvb[(m << 6) + lane];

  const int tbase = (tt << 5) + (w << 3);
  const float* qrow = qp + (((size_t)bh * TT + tbase) << 7);
  float* ob = qkvb + (((size_t)bh * TT + tbase) << 6);
#pragma unroll
  for (int tp = 0; tp < 4; ++tp) {
    const float* q0 = qrow + (tp << 8);
    float a0 = 0.f, a1 = 0.f;
#pragma unroll
    for (int m = 0; m < 128; ++m) {
      a0 = fmaf(q0[m], kvr[m], a0);
      a1 = fmaf(q0[128 + m], kvr[m], a1);
    }
    ob[(tp << 7) + lane] = a0;
    ob[(tp << 7) + 64 + lane] = a1;
  }
}

// ---------------------------------------------------------------------------
// Kernel D: banded local attention. Grid 1024, XCD-chunk swizzled, ~32 KB LDS.
// kf is RAW here; dots_prime terms are fixed up by kscale.
// ---------------------------------------------------------------------------
__global__ __launch_bounds__(256, 4) void band_kernel(
    const float* __restrict__ Q, const float* __restrict__ K,
    const float* __restrict__ V,
    const float* __restrict__ qp, const float* __restrict__ kp,
    const float* __restrict__ qkvb, const float* __restrict__ ksum,
    const float* __restrict__ qstab, const unsigned int* __restrict__ kmax,
    float* __restrict__ out)
{
  __shared__ __align__(16) float bufA[16][68];   // q / qp chunks
  __shared__ __align__(16) float bufB[80][68];   // k / kp chunks / v
  __shared__ float dT[80 * 17];                  // dots transposed [r][t]
  __shared__ float ksum_s[128];
  __shared__ float pls_s[16];
  __shared__ float psb[16];

  const int g = blockIdx.x;
  const int lg = ((g & 7) << 7) | (g >> 3);      // XCD chunk swizzle (1024 wgs)
  const int bh = lg >> 6, tile = lg & 63;
  const int b = bh >> 3, h = bh & 7;
  const int t0 = tile << 4;
  const int k0 = t0 - 32;
  const int tid = threadIdx.x;
  const float kmaxv = __uint_as_float(kmax[bh]);
  const float kscale = RSQRT_M / kmaxv;

  const float* Kbase = K + (((size_t)b * TT * HH + h) << 6);
  const float* Vbase = V + (((size_t)b * TT * HH + h) << 6);
  const float* Qbase = Q + (((size_t)b * TT * HH + h) << 6);
  const float* kpb = kp + (((size_t)bh * TT) << 7);
  const float* qpb = qp + (((size_t)bh * TT) << 7);

  // ---- initial staging: q->A, k->B, ksum, pls ----
  {
    const int r = tid >> 4, c4 = (tid & 15) << 2;
    *(float4*)&bufA[r][c4] = *(const float4*)&Qbase[(size_t)(t0 + r) * 512 + c4];
  }
#pragma unroll
  for (int it = 0; it < 5; ++it) {
    const int idx = (it << 8) + tid;
    const int r = idx >> 4, c4 = (idx & 15) << 2;
    const int tg = min(max(k0 + r, 0), TT - 1);
    *(float4*)&bufB[r][c4] = *(const float4*)&Kbase[(size_t)tg * 512 + c4];
  }
  if (tid < 128) ksum_s[tid] = ksum[(bh << 7) + tid];
  if (tid >= 128 && tid < 144) {
    const int r = tid - 128;
    pls_s[r] = qstab[(size_t)bh * TT + t0 + r] + __logf(kmaxv);
  }
  __syncthreads();

  const int tq = tid >> 4;            // query row 0..15
  const int r0 = (tid & 15) * 5;      // key rows r0..r0+4

  // ---- GEMM1: QK (16 x 80 x 64) ----
  float acc1[5] = {0.f, 0.f, 0.f, 0.f, 0.f};
#pragma unroll
  for (int cc = 0; cc < 16; ++cc) {
    const float4 a4 = *(const float4*)&bufA[tq][cc << 2];
#pragma unroll
    for (int i = 0; i < 5; ++i) {
      const float4 b4 = *(const float4*)&bufB[r0 + i][cc << 2];
      acc1[i] = fmaf(a4.x, b4.x, acc1[i]);
      acc1[i] = fmaf(a4.y, b4.y, acc1[i]);
      acc1[i] = fmaf(a4.z, b4.z, acc1[i]);
      acc1[i] = fmaf(a4.w, b4.w, acc1[i]);
    }
  }
  __syncthreads();

  // ---- GEMM2: dots_prime RAW (16 x 80 x 128), two 64-col chunks ----
  float acc2[5] = {0.f, 0.f, 0.f, 0.f, 0.f};
#pragma unroll 1
  for (int ch = 0; ch < 2; ++ch) {
    const int co = ch << 6;
    {
      const int r = tid >> 4, c4 = (tid & 15) << 2;
      *(float4*)&bufA[r][c4] = *(const float4*)&qpb[((size_t)(t0 + r) << 7) + co + c4];
    }
#pragma unroll
    for (int it = 0; it < 5; ++it) {
      const int idx = (it << 8) + tid;
      const int r = idx >> 4, c4 = (idx & 15) << 2;
      const int tg = min(max(k0 + r, 0), TT - 1);
      *(float4*)&bufB[r][c4] = *(const float4*)&kpb[((size_t)tg << 7) + co + c4];
    }
    __syncthreads();
#pragma unroll
    for (int cc = 0; cc < 16; ++cc) {
      const float4 a4 = *(const float4*)&bufA[tq][cc << 2];
#pragma unroll
      for (int i = 0; i < 5; ++i) {
        const float4 b4 = *(const float4*)&bufB[r0 + i][cc << 2];
        acc2[i] = fmaf(a4.x, b4.x, acc2[i]);
        acc2[i] = fmaf(a4.y, b4.y, acc2[i]);
        acc2[i] = fmaf(a4.z, b4.z, acc2[i]);
        acc2[i] = fmaf(a4.w, b4.w, acc2[i]);
      }
    }
    __syncthreads();
  }

  // ---- stage v->B (writes are after the barrier above) ----
#pragma unroll
  for (int it = 0; it < 5; ++it) {
    const int idx = (it << 8) + tid;
    const int r = idx >> 4, c4 = (idx & 15) << 2;
    const int tg = min(max(k0 + r, 0), TT - 1);
    *(float4*)&bufB[r][c4] = *(const float4*)&Vbase[(size_t)tg * 512 + c4];
  }

  // ---- P3: in-register masking + reductions + log-space norm + dots ----
  {
    float qkt[5], dpt[5];
#pragma unroll
    for (int i = 0; i < 5; ++i) {
      const int r = r0 + i;
      const int j = r - tq;
      const int gk = k0 + r;
      const bool valid = (j >= 0) && (j < 64) && (gk >= 0) && (gk < TT);
      qkt[i] = valid ? TEMP * acc1[i] : NEGINF;
      dpt[i] = valid ? kscale * acc2[i] : 0.f;
    }
    float mx = qkt[0];
#pragma unroll
    for (int i = 1; i < 5; ++i) mx = fmaxf(mx, qkt[i]);
    mx = fmaxf(mx, __shfl_xor(mx, 1));
    mx = fmaxf(mx, __shfl_xor(mx, 2));
    mx = fmaxf(mx, __shfl_xor(mx, 4));
    mx = fmaxf(mx, __shfl_xor(mx, 8));

    float se = 0.f, dps = 0.f;
#pragma unroll
    for (int i = 0; i < 5; ++i) {
      se += __expf(qkt[i] - mx);
      dps += dpt[i];
    }
    float qk1 = 0.f;
    const float* qrow = qpb + ((size_t)(t0 + tq) << 7);
#pragma unroll
    for (int ii = 0; ii < 8; ++ii) {
      const int m = (tid & 15) + (ii << 4);
      qk1 = fmaf(qrow[m], ksum_s[m], qk1);
    }
    se  += __shfl_xor(se, 1);  se  += __shfl_xor(se, 2);
    se  += __shfl_xor(se, 4);  se  += __shfl_xor(se, 8);
    dps += __shfl_xor(dps, 1); dps += __shfl_xor(dps, 2);
    dps += __shfl_xor(dps, 4); dps += __shfl_xor(dps, 8);
    qk1 += __shfl_xor(qk1, 1); qk1 += __shfl_xor(qk1, 2);
    qk1 += __shfl_xor(qk1, 4); qk1 += __shfl_xor(qk1, 8);

    const float pls = pls_s[tq];
    const float lse = mx + __logf(se);
    const float lr = fmaxf(qk1 - dps, 1e-24f);
    const float lrl = __logf(lr) + pls;
    const float aa = fmaxf(lse, lrl), bb = fminf(lse, lrl);
    const float ln = aa + log1pf(__expf(bb - aa));
    const float ps = __expf(pls - ln);
    if ((tid & 15) == 0) psb[tq] = ps;
#pragma unroll
    for (int i = 0; i < 5; ++i) {
      const float d = __expf(qkt[i] - ln) - dpt[i] * ps;
      dT[(r0 + i) * 17 + tq] = d;
    }
  }
  __syncthreads();

  // ---- P5: out_local = dots @ v_win (+ qkv * ps epilogue) ----
  {
    const int t5 = tid >> 4, dg = tid & 15, d0c = dg << 2;
    float a0 = 0.f, a1 = 0.f, a2 = 0.f, a3 = 0.f;
#pragma unroll
    for (int j = 0; j < 64; ++j) {
      const int jj = (j + dg) & 63;     // stagger to spread LDS banks
      const int r = t5 + jj;
      const float dv = dT[r * 17 + t5];
      const float4 v4 = *(const float4*)&bufB[r][d0c];
      a0 = fmaf(dv, v4.x, a0);
      a1 = fmaf(dv, v4.y, a1);
      a2 = fmaf(dv, v4.z, a2);
      a3 = fmaf(dv, v4.w, a3);
    }
    const float ps = psb[t5];
    const float4 q4 = *(const float4*)&qkvb[(((size_t)bh * TT + t0 + t5) << 6) + d0c];
    a0 = fmaf(q4.x, ps, a0);
    a1 = fmaf(q4.y, ps, a1);
    a2 = fmaf(q4.z, ps, a2);
    a3 = fmaf(q4.w, ps, a3);
    float* ob = out + ((((size_t)b * TT + t0 + t5) * HH + h) << 6) + d0c;
    *(float4*)ob = make_float4(a0, a1, a2, a3);
  }
}

extern "C" void kernel_launch(void* const* d_in, const int* in_sizes, int n_in,
                              void* d_out, int out_size, void* d_ws, size_t ws_size,
                              hipStream_t stream) {
  (void)in_sizes; (void)n_in; (void)out_size; (void)ws_size;
  const float* Q    = (const float*)d_in[0];
  const float* K    = (const float*)d_in[1];
  const float* V    = (const float*)d_in[2];
  const float* proj = (const float*)d_in[3];
  float* out = (float*)d_out;
  char* ws = (char*)d_ws;

  float*        qp    = (float*)(ws + OFF_QP);
  float*        kf    = (float*)(ws + OFF_KF);
  float*        qkvb  = (float*)(ws + OFF_QKV);
  float*        kvp   = (float*)(ws + OFF_KVP);
  float*        kv    = (float*)(ws + OFF_KV);
  float*        ksum  = (float*)(ws + OFF_KSUM);
  unsigned int* kmax  = (unsigned int*)(ws + OFF_KMAX);
  float*        qstab = (float*)(ws + OFF_QSTAB);
  float*        ksump = (float*)(ws + OFF_KSUMP);

  hipMemsetAsync(ws + OFF_KMAX, 0, 64, stream);
  feat_kernel<<<512, 256, 0, stream>>>(Q, K, proj, qp, kf, qstab, kmax);
  kv_partial<<<128, 256, 0, stream>>>(V, kf, kvp, ksump);
  kv_reduce<<<136, 256, 0, stream>>>(kvp, ksump, kmax, kv, ksum);
  qkv_kernel<<<512, 256, 0, stream>>>(qp, kv, qkvb);
  band_kernel<<<1024, 256, 0, stream>>>(Q, K, V, qp, kf, qkvb, ksum, qstab, kmax, out);
}

// Round 4
// 95.365 us; speedup vs baseline: 2.5984x; 1.1670x over previous
//
#include <hip/hip_runtime.h>

#define TT 1024
#define HH 8
#define EE 64
#define MM 128
#define NBH 16

#define NORMALIZER 0.35355339059327379f
#define RSQRT_M    0.08838834764831845f
#define TEMP       0.125f
#define NEGINF     -1e24f

// ws byte offsets
#define OFF_QP    0u            // [BH][T][M] f32  8 MB   q_prime (scaled)
#define OFF_KF    8388608u      // [BH][T][M] f32  8 MB   exp(logfeat_k) RAW
#define OFF_KVP   16777216u     // [BH][8][M][E] f32 4 MB unscaled kv partials
#define OFF_KV    20971520u     // [BH][M][E] f32  512 KB (scaled)
#define OFF_KSUM  21495808u     // [BH][M]    f32  8 KB   (scaled)
#define OFF_QSTAB 21504064u     // [BH][T]    f32  64 KB
#define OFF_KSUMP 21569600u     // [BH][8][M] f32  64 KB  (unscaled partials)
#define OFF_WTMAX 21635136u     // [BH][16]   f32  1 KB   per-tile k logfeat max

// ---------------------------------------------------------------------------
// Kernel A: FAVOR+ features. Grid 512 = 2 paths * 16 bh * 16 rowtiles(64).
// k-path stores per-tile max (log domain) via plain store — no atomics.
// ---------------------------------------------------------------------------
__global__ __launch_bounds__(256, 2) void feat_kernel(
    const float* __restrict__ Q, const float* __restrict__ K,
    const float* __restrict__ proj,
    float* __restrict__ qp, float* __restrict__ kf,
    float* __restrict__ qstab, float* __restrict__ wtmax)
{
  __shared__ float xsT[64][65];   // [e][row]
  __shared__ float Mh[64][4];

  const int bid  = blockIdx.x;
  const int path = bid >> 8;          // 0=q, 1=k
  const int bh   = (bid >> 4) & 15;
  const int rt   = bid & 15;
  const int b = bh >> 3, h = bh & 7;
  const int t0 = rt << 6;
  const int tid = threadIdx.x;

  const float* x = path ? K : Q;
  const float* xbase = x + (((size_t)b * TT * HH + h) << 6);
#pragma unroll
  for (int it = 0; it < 4; ++it) {
    const int idx = (it << 8) + tid;
    const int r = idx >> 4, c = (idx & 15) << 2;
    const float4 f4 = *(const float4*)&xbase[(size_t)(t0 + r) * 512 + c];
    xsT[c + 0][r] = f4.x; xsT[c + 1][r] = f4.y;
    xsT[c + 2][r] = f4.z; xsT[c + 3][r] = f4.w;
  }
  __syncthreads();

  const int lane = tid & 63;
  const int w = __builtin_amdgcn_readfirstlane(tid >> 6);
  float xv[64];
  float diag = 0.f;
#pragma unroll
  for (int c = 0; c < 64; ++c) { xv[c] = xsT[c][lane]; diag = fmaf(xv[c], xv[c], diag); }
  diag *= 0.0625f;   // 0.5*temp

  float lf[32];
  float mx = -3e30f;
  const int mbase = w << 5;
  for (int mm = 0; mm < 32; ++mm) {
    const float* pr = proj + ((mbase + mm) << 6);
    float a0 = 0.f, a1 = 0.f;
#pragma unroll
    for (int c = 0; c < 64; c += 2) {
      a0 = fmaf(xv[c], pr[c], a0);
      a1 = fmaf(xv[c + 1], pr[c + 1], a1);
    }
    const float v = fmaf(NORMALIZER, a0 + a1, -diag);
    lf[mm] = v;
    mx = fmaxf(mx, v);
  }
  Mh[lane][w] = mx;
  __syncthreads();
  const float m0 = fmaxf(fmaxf(Mh[lane][0], Mh[lane][1]), fmaxf(Mh[lane][2], Mh[lane][3]));

  float ov[32];
  if (path == 0) {
#pragma unroll
    for (int mm = 0; mm < 32; ++mm) ov[mm] = RSQRT_M * __expf(lf[mm] - m0);
    if (w == 0) qstab[(size_t)bh * TT + t0 + lane] = m0;
  } else {
#pragma unroll
    for (int mm = 0; mm < 32; ++mm) ov[mm] = __expf(lf[mm]);
    if (w == 0) {
      float bm = m0;   // m0 = this row's max over all 128 m
#pragma unroll
      for (int off = 1; off < 64; off <<= 1) bm = fmaxf(bm, __shfl_xor(bm, off));
      if (lane == 0) wtmax[(bh << 4) + rt] = bm;   // log-domain tile max
    }
  }
  float* dst = (path ? kf : qp) + (((size_t)bh * TT + t0 + lane) << 7) + mbase;
#pragma unroll
  for (int q4 = 0; q4 < 8; ++q4)
    *(float4*)&dst[q4 << 2] =
        make_float4(ov[q4 * 4], ov[q4 * 4 + 1], ov[q4 * 4 + 2], ov[q4 * 4 + 3]);
}

// ---------------------------------------------------------------------------
// Kernel B: UNSCALED partial kv + ksum per 128-row s-tile. No atomics.
// Grid 128 = 16 bh * 8 tiles. Two 64-row LDS chunks, 50 KB.
// ---------------------------------------------------------------------------
__global__ __launch_bounds__(256, 2) void kv_partial(
    const float* __restrict__ V, const float* __restrict__ kf,
    float* __restrict__ kvp, float* __restrict__ ksump)
{
  __shared__ __align__(16) float smem[64 * 132 + 64 * 68];
  float (*kp_s)[132] = (float(*)[132])smem;
  float (*vs)[68] = (float(*)[68])(smem + 64 * 132);

  const int bid = blockIdx.x;
  const int bh = bid >> 3, st = bid & 7;
  const int b = bh >> 3, h = bh & 7;
  const int tid = threadIdx.x;

  const int h2 = tid >> 7;                 // s half within chunk
  const int m0 = ((tid & 127) >> 3) << 3;  // 16 tiles of 8 m
  const int d0 = (tid & 7) << 3;           // 8 tiles of 8 d
  float acc[8][8];
#pragma unroll
  for (int i = 0; i < 8; ++i)
#pragma unroll
    for (int j = 0; j < 8; ++j) acc[i][j] = 0.f;
  float csum = 0.f;   // column sum for tid<128

#pragma unroll 1
  for (int ch = 0; ch < 2; ++ch) {
    const int row0 = (st << 7) + (ch << 6);
    const size_t base_kf = ((size_t)bh * TT + row0) << 7;
#pragma unroll
    for (int it = 0; it < 8; ++it) {
      const int idx = (it << 10) + (tid << 2);   // 64*128
      const int r = idx >> 7, c = idx & 127;
      *(float4*)&kp_s[r][c] = *(const float4*)&kf[base_kf + idx];
    }
#pragma unroll
    for (int it = 0; it < 4; ++it) {
      const int idx = (it << 10) + (tid << 2);   // 64*64
      const int r = idx >> 6, c = idx & 63;
      *(float4*)&vs[r][c] = *(const float4*)(V + ((((size_t)b * TT + row0 + r) * HH + h) << 6) + c);
    }
    __syncthreads();

    if (tid < 128) {
      float s = 0.f;
      for (int ss = 0; ss < 64; ++ss) s += kp_s[ss][tid];
      csum += s;
    }
    const int s0 = h2 << 5;
    for (int ss = s0; ss < s0 + 32; ++ss) {
      const float4 k0v = *(const float4*)&kp_s[ss][m0];
      const float4 k1v = *(const float4*)&kp_s[ss][m0 + 4];
      const float4 v0v = *(const float4*)&vs[ss][d0];
      const float4 v1v = *(const float4*)&vs[ss][d0 + 4];
      const float km[8] = {k0v.x,k0v.y,k0v.z,k0v.w,k1v.x,k1v.y,k1v.z,k1v.w};
      const float vd[8] = {v0v.x,v0v.y,v0v.z,v0v.w,v1v.x,v1v.y,v1v.z,v1v.w};
#pragma unroll
      for (int i = 0; i < 8; ++i)
#pragma unroll
        for (int j = 0; j < 8; ++j) acc[i][j] = fmaf(km[i], vd[j], acc[i][j]);
    }
    __syncthreads();
  }

  if (tid < 128) ksump[(bid << 7) + tid] = csum;

  float (*kvm)[68] = (float(*)[68])smem;   // 128x68 fits
  if (h2 == 0) {
#pragma unroll
    for (int i = 0; i < 8; ++i)
#pragma unroll
      for (int j = 0; j < 8; ++j) kvm[m0 + i][d0 + j] = acc[i][j];
  }
  __syncthreads();
  if (h2 == 1) {
#pragma unroll
    for (int i = 0; i < 8; ++i)
#pragma unroll
      for (int j = 0; j < 8; ++j) kvm[m0 + i][d0 + j] += acc[i][j];
  }
  __syncthreads();
  float* kvb = kvp + ((size_t)bid << 13);
#pragma unroll
  for (int it = 0; it < 8; ++it) {
    const int idx = (it << 10) + (tid << 2);
    const int m = idx >> 6, d = idx & 63;
    *(float4*)&kvb[idx] = make_float4(kvm[m][d], kvm[m][d + 1], kvm[m][d + 2], kvm[m][d + 3]);
  }
}

// ---------------------------------------------------------------------------
// Kernel B2: reduce 8 partials, apply scale = RSQRT_M * exp(-kml).
// Grid 136: blocks 0..127 -> kv (1024 elems each), 128..135 -> ksum.
// ---------------------------------------------------------------------------
__global__ __launch_bounds__(256, 4) void kv_reduce(
    const float* __restrict__ kvp, const float* __restrict__ ksump,
    const float* __restrict__ wtmax,
    float* __restrict__ kv, float* __restrict__ ksum)
{
  const int bid = blockIdx.x;
  const int tid = threadIdx.x;
  if (bid < 128) {
    const int g = (bid << 10) + (tid << 2);
    const int bh = g >> 13, idx = g & 8191;
    float kml = wtmax[bh << 4];
#pragma unroll
    for (int i = 1; i < 16; ++i) kml = fmaxf(kml, wtmax[(bh << 4) + i]);
    const float scale = RSQRT_M * __expf(-kml);
    float4 s = make_float4(0.f, 0.f, 0.f, 0.f);
#pragma unroll
    for (int p = 0; p < 8; ++p) {
      const float4 v = *(const float4*)&kvp[((((size_t)bh << 3) + p) << 13) + idx];
      s.x += v.x; s.y += v.y; s.z += v.z; s.w += v.w;
    }
    s.x *= scale; s.y *= scale; s.z *= scale; s.w *= scale;
    *(float4*)&kv[((size_t)bh << 13) + idx] = s;
  } else {
    const int g = ((bid - 128) << 8) + tid;
    const int bh = g >> 7, m = g & 127;
    float kml = wtmax[bh << 4];
#pragma unroll
    for (int i = 1; i < 16; ++i) kml = fmaxf(kml, wtmax[(bh << 4) + i]);
    const float scale = RSQRT_M * __expf(-kml);
    float s = 0.f;
#pragma unroll
    for (int p = 0; p < 8; ++p) s += ksump[(((bh << 3) + p) << 7) + m];
    ksum[(bh << 7) + m] = s * scale;
  }
}

// ---------------------------------------------------------------------------
// Kernel D: banded local attention with INLINE qkv (= q' @ kv) computation.
// Grid 1024 = 16 bh * 64 tiles(16 q), XCD-chunk swizzled. ~49.6 KB LDS,
// 3 blocks/CU. kf is RAW; dots_prime fixed up by kscale.
// ---------------------------------------------------------------------------
__global__ __launch_bounds__(256, 3) void band_kernel(
    const float* __restrict__ Q, const float* __restrict__ K,
    const float* __restrict__ V,
    const float* __restrict__ qp, const float* __restrict__ kp,
    const float* __restrict__ kv, const float* __restrict__ ksum,
    const float* __restrict__ qstab, const float* __restrict__ wtmax,
    float* __restrict__ out)
{
  __shared__ __align__(16) float bufA[16][68];   // q / qp chunks
  __shared__ __align__(16) float bufB[80][68];   // k / kp chunks / v
  __shared__ __align__(16) float kvs[64][68];    // kv chunk [m][d]
  __shared__ float dT[80 * 17];                  // dots transposed [r][t]
  __shared__ float ksum_s[128];
  __shared__ float pls_s[16];
  __shared__ float psb[16];

  const int g = blockIdx.x;
  const int lg = ((g & 7) << 7) | (g >> 3);      // XCD chunk swizzle (1024 wgs)
  const int bh = lg >> 6, tile = lg & 63;
  const int b = bh >> 3, h = bh & 7;
  const int t0 = tile << 4;
  const int k0 = t0 - 32;
  const int tid = threadIdx.x;

  float kml = wtmax[bh << 4];
#pragma unroll
  for (int i = 1; i < 16; ++i) kml = fmaxf(kml, wtmax[(bh << 4) + i]);
  const float kscale = RSQRT_M * __expf(-kml);

  const float* Kbase = K + (((size_t)b * TT * HH + h) << 6);
  const float* Vbase = V + (((size_t)b * TT * HH + h) << 6);
  const float* Qbase = Q + (((size_t)b * TT * HH + h) << 6);
  const float* kpb = kp + (((size_t)bh * TT) << 7);
  const float* qpb = qp + (((size_t)bh * TT) << 7);
  const float* kvb = kv + ((size_t)bh << 13);

  // ---- initial staging: q->A, k->B, ksum, pls ----
  {
    const int r = tid >> 4, c4 = (tid & 15) << 2;
    *(float4*)&bufA[r][c4] = *(const float4*)&Qbase[(size_t)(t0 + r) * 512 + c4];
  }
#pragma unroll
  for (int it = 0; it < 5; ++it) {
    const int idx = (it << 8) + tid;
    const int r = idx >> 4, c4 = (idx & 15) << 2;
    const int tg = min(max(k0 + r, 0), TT - 1);
    *(float4*)&bufB[r][c4] = *(const float4*)&Kbase[(size_t)tg * 512 + c4];
  }
  if (tid < 128) ksum_s[tid] = ksum[(bh << 7) + tid];
  if (tid >= 128 && tid < 144) {
    const int r = tid - 128;
    pls_s[r] = qstab[(size_t)bh * TT + t0 + r] + kml;
  }
  __syncthreads();

  const int tq = tid >> 4;            // query row 0..15
  const int dg = tid & 15;
  const int r0 = dg * 5;              // key rows r0..r0+4
  const int d0c = dg << 2;            // d columns for qkv/P5

  // ---- GEMM1: QK (16 x 80 x 64) ----
  float acc1[5] = {0.f, 0.f, 0.f, 0.f, 0.f};
#pragma unroll
  for (int cc = 0; cc < 16; ++cc) {
    const float4 a4 = *(const float4*)&bufA[tq][cc << 2];
#pragma unroll
    for (int i = 0; i < 5; ++i) {
      const float4 b4 = *(const float4*)&bufB[r0 + i][cc << 2];
      acc1[i] = fmaf(a4.x, b4.x, acc1[i]);
      acc1[i] = fmaf(a4.y, b4.y, acc1[i]);
      acc1[i] = fmaf(a4.z, b4.z, acc1[i]);
      acc1[i] = fmaf(a4.w, b4.w, acc1[i]);
    }
  }
  __syncthreads();

  // ---- GEMM2 (dots_prime RAW) + inline qkv + qk1, two 64-col chunks ----
  float acc2[5] = {0.f, 0.f, 0.f, 0.f, 0.f};
  float qkvr[4] = {0.f, 0.f, 0.f, 0.f};
  float qk1 = 0.f;
#pragma unroll 1
  for (int ch = 0; ch < 2; ++ch) {
    const int co = ch << 6;
    {
      const int r = tid >> 4, c4 = (tid & 15) << 2;
      *(float4*)&bufA[r][c4] = *(const float4*)&qpb[((size_t)(t0 + r) << 7) + co + c4];
    }
#pragma unroll
    for (int it = 0; it < 5; ++it) {
      const int idx = (it << 8) + tid;
      const int r = idx >> 4, c4 = (idx & 15) << 2;
      const int tg = min(max(k0 + r, 0), TT - 1);
      *(float4*)&bufB[r][c4] = *(const float4*)&kpb[((size_t)tg << 7) + co + c4];
    }
#pragma unroll
    for (int it = 0; it < 4; ++it) {
      const int idx = (it << 8) + tid;
      const int r = idx >> 4, c4 = (idx & 15) << 2;
      *(float4*)&kvs[r][c4] = *(const float4*)&kvb[((co + r) << 6) + c4];
    }
    __syncthreads();
#pragma unroll
    for (int cc = 0; cc < 16; ++cc) {
      const float4 a4 = *(const float4*)&bufA[tq][cc << 2];
#pragma unroll
      for (int i = 0; i < 5; ++i) {
        const float4 b4 = *(const float4*)&bufB[r0 + i][cc << 2];
        acc2[i] = fmaf(a4.x, b4.x, acc2[i]);
        acc2[i] = fmaf(a4.y, b4.y, acc2[i]);
        acc2[i] = fmaf(a4.z, b4.z, acc2[i]);
        acc2[i] = fmaf(a4.w, b4.w, acc2[i]);
      }
    }
    // qkv partial: qkvr[d] += sum_m qp[tq][m] * kv[m][d]
#pragma unroll
    for (int mq = 0; mq < 16; ++mq) {
      const float4 a4 = *(const float4*)&bufA[tq][mq << 2];
      const float4 k0v = *(const float4*)&kvs[(mq << 2) + 0][d0c];
      const float4 k1v = *(const float4*)&kvs[(mq << 2) + 1][d0c];
      const float4 k2v = *(const float4*)&kvs[(mq << 2) + 2][d0c];
      const float4 k3v = *(const float4*)&kvs[(mq << 2) + 3][d0c];
      qkvr[0] = fmaf(a4.x, k0v.x, qkvr[0]); qkvr[1] = fmaf(a4.x, k0v.y, qkvr[1]);
      qkvr[2] = fmaf(a4.x, k0v.z, qkvr[2]); qkvr[3] = fmaf(a4.x, k0v.w, qkvr[3]);
      qkvr[0] = fmaf(a4.y, k1v.x, qkvr[0]); qkvr[1] = fmaf(a4.y, k1v.y, qkvr[1]);
      qkvr[2] = fmaf(a4.y, k1v.z, qkvr[2]); qkvr[3] = fmaf(a4.y, k1v.w, qkvr[3]);
      qkvr[0] = fmaf(a4.z, k2v.x, qkvr[0]); qkvr[1] = fmaf(a4.z, k2v.y, qkvr[1]);
      qkvr[2] = fmaf(a4.z, k2v.z, qkvr[2]); qkvr[3] = fmaf(a4.z, k2v.w, qkvr[3]);
      qkvr[0] = fmaf(a4.w, k3v.x, qkvr[0]); qkvr[1] = fmaf(a4.w, k3v.y, qkvr[1]);
      qkvr[2] = fmaf(a4.w, k3v.z, qkvr[2]); qkvr[3] = fmaf(a4.w, k3v.w, qkvr[3]);
    }
    // qk1 partial over this chunk's m (each lane of the 16-group owns 4 m)
#pragma unroll
    for (int i = 0; i < 4; ++i) {
      const int m = dg + (i << 4);
      qk1 = fmaf(bufA[tq][m], ksum_s[co + m], qk1);
    }
    __syncthreads();
  }

  // ---- stage v->B (bufB free after chunk-loop barrier) ----
#pragma unroll
  for (int it = 0; it < 5; ++it) {
    const int idx = (it << 8) + tid;
    const int r = idx >> 4, c4 = (idx & 15) << 2;
    const int tg = min(max(k0 + r, 0), TT - 1);
    *(float4*)&bufB[r][c4] = *(const float4*)&Vbase[(size_t)tg * 512 + c4];
  }

  // ---- P3: in-register masking + reductions + log-space norm + dots ----
  {
    float qkt[5], dpt[5];
#pragma unroll
    for (int i = 0; i < 5; ++i) {
      const int r = r0 + i;
      const int j = r - tq;
      const int gk = k0 + r;
      const bool valid = (j >= 0) && (j < 64) && (gk >= 0) && (gk < TT);
      qkt[i] = valid ? TEMP * acc1[i] : NEGINF;
      dpt[i] = valid ? kscale * acc2[i] : 0.f;
    }
    float mx = qkt[0];
#pragma unroll
    for (int i = 1; i < 5; ++i) mx = fmaxf(mx, qkt[i]);
    mx = fmaxf(mx, __shfl_xor(mx, 1));
    mx = fmaxf(mx, __shfl_xor(mx, 2));
    mx = fmaxf(mx, __shfl_xor(mx, 4));
    mx = fmaxf(mx, __shfl_xor(mx, 8));

    float se = 0.f, dps = 0.f;
#pragma unroll
    for (int i = 0; i < 5; ++i) {
      se += __expf(qkt[i] - mx);
      dps += dpt[i];
    }
    float qk1r = qk1;
    se  += __shfl_xor(se, 1);  se  += __shfl_xor(se, 2);
    se  += __shfl_xor(se, 4);  se  += __shfl_xor(se, 8);
    dps += __shfl_xor(dps, 1); dps += __shfl_xor(dps, 2);
    dps += __shfl_xor(dps, 4); dps += __shfl_xor(dps, 8);
    qk1r += __shfl_xor(qk1r, 1); qk1r += __shfl_xor(qk1r, 2);
    qk1r += __shfl_xor(qk1r, 4); qk1r += __shfl_xor(qk1r, 8);

    const float pls = pls_s[tq];
    const float lse = mx + __logf(se);
    const float lr = fmaxf(qk1r - dps, 1e-24f);
    const float lrl = __logf(lr) + pls;
    const float aa = fmaxf(lse, lrl), bb = fminf(lse, lrl);
    const float ln = aa + log1pf(__expf(bb - aa));
    const float ps = __expf(pls - ln);
    if (dg == 0) psb[tq] = ps;
#pragma unroll
    for (int i = 0; i < 5; ++i) {
      const float d = __expf(qkt[i] - ln) - dpt[i] * ps;
      dT[(r0 + i) * 17 + tq] = d;
    }
  }
  __syncthreads();

  // ---- P5: out_local = dots @ v_win + qkvr * ps epilogue ----
  {
    float a0 = 0.f, a1 = 0.f, a2 = 0.f, a3 = 0.f;
#pragma unroll
    for (int j = 0; j < 64; ++j) {
      const int jj = (j + dg) & 63;     // stagger to spread LDS banks
      const int r = tq + jj;
      const float dv = dT[r * 17 + tq];
      const float4 v4 = *(const float4*)&bufB[r][d0c];
      a0 = fmaf(dv, v4.x, a0);
      a1 = fmaf(dv, v4.y, a1);
      a2 = fmaf(dv, v4.z, a2);
      a3 = fmaf(dv, v4.w, a3);
    }
    const float ps = psb[tq];
    a0 = fmaf(qkvr[0], ps, a0);
    a1 = fmaf(qkvr[1], ps, a1);
    a2 = fmaf(qkvr[2], ps, a2);
    a3 = fmaf(qkvr[3], ps, a3);
    float* ob = out + ((((size_t)b * TT + t0 + tq) * HH + h) << 6) + d0c;
    *(float4*)ob = make_float4(a0, a1, a2, a3);
  }
}

extern "C" void kernel_launch(void* const* d_in, const int* in_sizes, int n_in,
                              void* d_out, int out_size, void* d_ws, size_t ws_size,
                              hipStream_t stream) {
  (void)in_sizes; (void)n_in; (void)out_size; (void)ws_size;
  const float* Q    = (const float*)d_in[0];
  const float* K    = (const float*)d_in[1];
  const float* V    = (const float*)d_in[2];
  const float* proj = (const float*)d_in[3];
  float* out = (float*)d_out;
  char* ws = (char*)d_ws;

  float* qp    = (float*)(ws + OFF_QP);
  float* kf    = (float*)(ws + OFF_KF);
  float* kvp   = (float*)(ws + OFF_KVP);
  float* kv    = (float*)(ws + OFF_KV);
  float* ksum  = (float*)(ws + OFF_KSUM);
  float* qstab = (float*)(ws + OFF_QSTAB);
  float* ksump = (float*)(ws + OFF_KSUMP);
  float* wtmax = (float*)(ws + OFF_WTMAX);

  feat_kernel<<<512, 256, 0, stream>>>(Q, K, proj, qp, kf, qstab, wtmax);
  kv_partial<<<128, 256, 0, stream>>>(V, kf, kvp, ksump);
  kv_reduce<<<136, 256, 0, stream>>>(kvp, ksump, wtmax, kv, ksum);
  band_kernel<<<1024, 256, 0, stream>>>(Q, K, V, qp, kf, kv, ksum, qstab, wtmax, out);
}

// Round 5
// 79.686 us; speedup vs baseline: 3.1096x; 1.1968x over previous
//
#include <hip/hip_runtime.h>

#define TT 1024
#define HH 8
#define EE 64
#define MM 128
#define NBH 16

#define NORMALIZER 0.35355339059327379f
#define RSQRT_M    0.08838834764831845f
#define TEMP       0.125f
#define NEGINF     -1e24f

// ws byte offsets
#define OFF_QP    0u            // [BH][T][M] f32  8 MB   q_prime (scaled)
#define OFF_KF    8388608u      // [BH][T][M] f32  8 MB   exp(logfeat_k) RAW
#define OFF_KVP   16777216u     // [BH][16][M][E] f32 8 MB unscaled kv partials
#define OFF_KV    25165824u     // [BH][M][E] f32  512 KB (scaled)
#define OFF_KSUM  25690112u     // [BH][M]    f32  8 KB   (scaled)
#define OFF_QSTAB 25698304u     // [BH][T]    f32  64 KB
#define OFF_KSUMP 25763840u     // [BH][16][M] f32 128 KB (unscaled partials)
#define OFF_WTMAX 25894912u     // [BH][16]   f32  1 KB   per-tile k logfeat max

// ---------------------------------------------------------------------------
// Kernel A: FAVOR+ features. Grid 512 = 2 paths * 16 bh * 16 rowtiles(64).
// ---------------------------------------------------------------------------
__global__ __launch_bounds__(256, 2) void feat_kernel(
    const float* __restrict__ Q, const float* __restrict__ K,
    const float* __restrict__ proj,
    float* __restrict__ qp, float* __restrict__ kf,
    float* __restrict__ qstab, float* __restrict__ wtmax)
{
  __shared__ float xsT[64][65];   // [e][row]
  __shared__ float Mh[64][4];

  const int bid  = blockIdx.x;
  const int path = bid >> 8;          // 0=q, 1=k
  const int bh   = (bid >> 4) & 15;
  const int rt   = bid & 15;
  const int b = bh >> 3, h = bh & 7;
  const int t0 = rt << 6;
  const int tid = threadIdx.x;

  const float* x = path ? K : Q;
  const float* xbase = x + (((size_t)b * TT * HH + h) << 6);
#pragma unroll
  for (int it = 0; it < 4; ++it) {
    const int idx = (it << 8) + tid;
    const int r = idx >> 4, c = (idx & 15) << 2;
    const float4 f4 = *(const float4*)&xbase[(size_t)(t0 + r) * 512 + c];
    xsT[c + 0][r] = f4.x; xsT[c + 1][r] = f4.y;
    xsT[c + 2][r] = f4.z; xsT[c + 3][r] = f4.w;
  }
  __syncthreads();

  const int lane = tid & 63;
  const int w = __builtin_amdgcn_readfirstlane(tid >> 6);
  float xv[64];
  float diag = 0.f;
#pragma unroll
  for (int c = 0; c < 64; ++c) { xv[c] = xsT[c][lane]; diag = fmaf(xv[c], xv[c], diag); }
  diag *= 0.0625f;   // 0.5*temp

  float lf[32];
  float mx = -3e30f;
  const int mbase = w << 5;
  for (int mm = 0; mm < 32; ++mm) {
    const float* pr = proj + ((mbase + mm) << 6);
    float a0 = 0.f, a1 = 0.f;
#pragma unroll
    for (int c = 0; c < 64; c += 2) {
      a0 = fmaf(xv[c], pr[c], a0);
      a1 = fmaf(xv[c + 1], pr[c + 1], a1);
    }
    const float v = fmaf(NORMALIZER, a0 + a1, -diag);
    lf[mm] = v;
    mx = fmaxf(mx, v);
  }
  Mh[lane][w] = mx;
  __syncthreads();
  const float m0 = fmaxf(fmaxf(Mh[lane][0], Mh[lane][1]), fmaxf(Mh[lane][2], Mh[lane][3]));

  float ov[32];
  if (path == 0) {
#pragma unroll
    for (int mm = 0; mm < 32; ++mm) ov[mm] = RSQRT_M * __expf(lf[mm] - m0);
    if (w == 0) qstab[(size_t)bh * TT + t0 + lane] = m0;
  } else {
#pragma unroll
    for (int mm = 0; mm < 32; ++mm) ov[mm] = __expf(lf[mm]);
    if (w == 0) {
      float bm = m0;   // per-row max over all 128 m
#pragma unroll
      for (int off = 1; off < 64; off <<= 1) bm = fmaxf(bm, __shfl_xor(bm, off));
      if (lane == 0) wtmax[(bh << 4) + rt] = bm;   // log-domain tile max
    }
  }
  float* dst = (path ? kf : qp) + (((size_t)bh * TT + t0 + lane) << 7) + mbase;
#pragma unroll
  for (int q4 = 0; q4 < 8; ++q4)
    *(float4*)&dst[q4 << 2] =
        make_float4(ov[q4 * 4], ov[q4 * 4 + 1], ov[q4 * 4 + 2], ov[q4 * 4 + 3]);
}

// ---------------------------------------------------------------------------
// Kernel B: UNSCALED partial kv + ksum per 64-row s-tile. Grid 256 (full GPU).
// ---------------------------------------------------------------------------
__global__ __launch_bounds__(256, 2) void kv_partial(
    const float* __restrict__ V, const float* __restrict__ kf,
    float* __restrict__ kvp, float* __restrict__ ksump)
{
  __shared__ __align__(16) float smem[64 * 132 + 64 * 68];
  float (*kp_s)[132] = (float(*)[132])smem;
  float (*vs)[68] = (float(*)[68])(smem + 64 * 132);

  const int bid = blockIdx.x;
  const int bh = bid >> 4, st = bid & 15;
  const int b = bh >> 3, h = bh & 7;
  const int tid = threadIdx.x;
  const int row0 = st << 6;
  const size_t base_kf = ((size_t)bh * TT + row0) << 7;

#pragma unroll
  for (int it = 0; it < 8; ++it) {
    const int idx = (it << 10) + (tid << 2);   // 64*128
    const int r = idx >> 7, c = idx & 127;
    *(float4*)&kp_s[r][c] = *(const float4*)&kf[base_kf + idx];
  }
#pragma unroll
  for (int it = 0; it < 4; ++it) {
    const int idx = (it << 10) + (tid << 2);   // 64*64
    const int r = idx >> 6, c = idx & 63;
    *(float4*)&vs[r][c] = *(const float4*)(V + ((((size_t)b * TT + row0 + r) * HH + h) << 6) + c);
  }
  __syncthreads();

  if (tid < 128) {
    float s = 0.f;
    for (int ss = 0; ss < 64; ++ss) s += kp_s[ss][tid];
    ksump[(bid << 7) + tid] = s;
  }

  const int h2 = tid >> 7;                 // s half
  const int m0 = ((tid & 127) >> 3) << 3;  // 16 tiles of 8 m
  const int d0 = (tid & 7) << 3;           // 8 tiles of 8 d
  float acc[8][8];
#pragma unroll
  for (int i = 0; i < 8; ++i)
#pragma unroll
    for (int j = 0; j < 8; ++j) acc[i][j] = 0.f;

  const int s0 = h2 << 5;
  for (int ss = s0; ss < s0 + 32; ++ss) {
    const float4 k0v = *(const float4*)&kp_s[ss][m0];
    const float4 k1v = *(const float4*)&kp_s[ss][m0 + 4];
    const float4 v0v = *(const float4*)&vs[ss][d0];
    const float4 v1v = *(const float4*)&vs[ss][d0 + 4];
    const float km[8] = {k0v.x,k0v.y,k0v.z,k0v.w,k1v.x,k1v.y,k1v.z,k1v.w};
    const float vd[8] = {v0v.x,v0v.y,v0v.z,v0v.w,v1v.x,v1v.y,v1v.z,v1v.w};
#pragma unroll
    for (int i = 0; i < 8; ++i)
#pragma unroll
      for (int j = 0; j < 8; ++j) acc[i][j] = fmaf(km[i], vd[j], acc[i][j]);
  }
  __syncthreads();
  float (*kvm)[68] = (float(*)[68])smem;   // 128x68 fits
  if (h2 == 0) {
#pragma unroll
    for (int i = 0; i < 8; ++i)
#pragma unroll
      for (int j = 0; j < 8; ++j) kvm[m0 + i][d0 + j] = acc[i][j];
  }
  __syncthreads();
  if (h2 == 1) {
#pragma unroll
    for (int i = 0; i < 8; ++i)
#pragma unroll
      for (int j = 0; j < 8; ++j) kvm[m0 + i][d0 + j] += acc[i][j];
  }
  __syncthreads();
  float* kvb = kvp + ((size_t)bid << 13);
#pragma unroll
  for (int it = 0; it < 8; ++it) {
    const int idx = (it << 10) + (tid << 2);
    const int m = idx >> 6, d = idx & 63;
    *(float4*)&kvb[idx] = make_float4(kvm[m][d], kvm[m][d + 1], kvm[m][d + 2], kvm[m][d + 3]);
  }
}

// ---------------------------------------------------------------------------
// Kernel B2: reduce 16 partials, apply scale = RSQRT_M * exp(-kml).
// Grid 136: blocks 0..127 -> kv, 128..135 -> ksum.
// ---------------------------------------------------------------------------
__global__ __launch_bounds__(256, 4) void kv_reduce(
    const float* __restrict__ kvp, const float* __restrict__ ksump,
    const float* __restrict__ wtmax,
    float* __restrict__ kv, float* __restrict__ ksum)
{
  const int bid = blockIdx.x;
  const int tid = threadIdx.x;
  if (bid < 128) {
    const int g = (bid << 10) + (tid << 2);
    const int bh = g >> 13, idx = g & 8191;
    float kml = wtmax[bh << 4];
#pragma unroll
    for (int i = 1; i < 16; ++i) kml = fmaxf(kml, wtmax[(bh << 4) + i]);
    const float scale = RSQRT_M * __expf(-kml);
    float4 s = make_float4(0.f, 0.f, 0.f, 0.f);
#pragma unroll
    for (int p = 0; p < 16; ++p) {
      const float4 v = *(const float4*)&kvp[((((size_t)bh << 4) + p) << 13) + idx];
      s.x += v.x; s.y += v.y; s.z += v.z; s.w += v.w;
    }
    s.x *= scale; s.y *= scale; s.z *= scale; s.w *= scale;
    *(float4*)&kv[((size_t)bh << 13) + idx] = s;
  } else {
    const int g = ((bid - 128) << 8) + tid;
    const int bh = g >> 7, m = g & 127;
    float kml = wtmax[bh << 4];
#pragma unroll
    for (int i = 1; i < 16; ++i) kml = fmaxf(kml, wtmax[(bh << 4) + i]);
    const float scale = RSQRT_M * __expf(-kml);
    float s = 0.f;
#pragma unroll
    for (int p = 0; p < 16; ++p) s += ksump[(((bh << 4) + p) << 7) + m];
    ksum[(bh << 7) + m] = s * scale;
  }
}

// ---------------------------------------------------------------------------
// Kernel D: banded local attention, 32-q tiles, 2q x 6k register tiling.
// Grid 512 = 16 bh * 32 tiles, XCD-chunk swizzled. ~53 KB LDS, 3 blocks/CU.
// ---------------------------------------------------------------------------
__global__ __launch_bounds__(256, 3) void band_kernel(
    const float* __restrict__ Q, const float* __restrict__ K,
    const float* __restrict__ V,
    const float* __restrict__ qp, const float* __restrict__ kp,
    const float* __restrict__ kv, const float* __restrict__ ksum,
    const float* __restrict__ qstab, const float* __restrict__ wtmax,
    float* __restrict__ out)
{
  __shared__ __align__(16) float bufA[32][68];     // q / qp chunks
  __shared__ __align__(16) float bufB[96][68];     // k / kp chunks / v
  __shared__ __align__(16) float kvs_dT[64 * 68];  // kv chunk, then dT[96][33]
  __shared__ float ksum_s[128];
  __shared__ float pls_s[32];

  const int g = blockIdx.x;
  const int lg = ((g & 7) << 6) | (g >> 3);      // XCD chunk swizzle (512 wgs)
  const int bh = lg >> 5, tile = lg & 31;
  const int b = bh >> 3, h = bh & 7;
  const int t0 = tile << 5;
  const int k0 = t0 - 32;
  const int tid = threadIdx.x;

  float kml = wtmax[bh << 4];
#pragma unroll
  for (int i = 1; i < 16; ++i) kml = fmaxf(kml, wtmax[(bh << 4) + i]);
  const float kscale = RSQRT_M * __expf(-kml);

  const float* Kbase = K + (((size_t)b * TT * HH + h) << 6);
  const float* Vbase = V + (((size_t)b * TT * HH + h) << 6);
  const float* Qbase = Q + (((size_t)b * TT * HH + h) << 6);
  const float* kpb = kp + (((size_t)bh * TT) << 7);
  const float* qpb = qp + (((size_t)bh * TT) << 7);
  const float* kvb = kv + ((size_t)bh << 13);

  // ---- initial staging: q->A (2/thr), k->B (6/thr), ksum, pls ----
#pragma unroll
  for (int it = 0; it < 2; ++it) {
    const int idx = (it << 8) + tid;
    const int r = idx >> 4, c4 = (idx & 15) << 2;
    *(float4*)&bufA[r][c4] = *(const float4*)&Qbase[(size_t)(t0 + r) * 512 + c4];
  }
#pragma unroll
  for (int it = 0; it < 6; ++it) {
    const int idx = (it << 8) + tid;
    const int r = idx >> 4, c4 = (idx & 15) << 2;
    const int tg = min(max(k0 + r, 0), TT - 1);
    *(float4*)&bufB[r][c4] = *(const float4*)&Kbase[(size_t)tg * 512 + c4];
  }
  if (tid < 128) ksum_s[tid] = ksum[(bh << 7) + tid];
  if (tid >= 128 && tid < 160) {
    const int r = tid - 128;
    pls_s[r] = qstab[(size_t)bh * TT + t0 + r] + kml;
  }
  __syncthreads();

  const int tq = tid >> 4;            // q rows tq and tq+16
  const int dg = tid & 15;
  const int r6 = dg * 6;              // k rows r6..r6+5
  const int d0c = dg << 2;            // d cols for qkv/P5

  // ---- GEMM1: QK (32 x 96 x 64), col-staggered reads ----
  float acc1[2][6];
#pragma unroll
  for (int i = 0; i < 6; ++i) { acc1[0][i] = 0.f; acc1[1][i] = 0.f; }
#pragma unroll
  for (int cc = 0; cc < 16; ++cc) {
    const int col = ((cc + dg) & 15) << 2;
    const float4 a0 = *(const float4*)&bufA[tq][col];
    const float4 a1 = *(const float4*)&bufA[tq + 16][col];
#pragma unroll
    for (int i = 0; i < 6; ++i) {
      const float4 b4 = *(const float4*)&bufB[r6 + i][col];
      acc1[0][i] = fmaf(a0.x, b4.x, acc1[0][i]); acc1[0][i] = fmaf(a0.y, b4.y, acc1[0][i]);
      acc1[0][i] = fmaf(a0.z, b4.z, acc1[0][i]); acc1[0][i] = fmaf(a0.w, b4.w, acc1[0][i]);
      acc1[1][i] = fmaf(a1.x, b4.x, acc1[1][i]); acc1[1][i] = fmaf(a1.y, b4.y, acc1[1][i]);
      acc1[1][i] = fmaf(a1.z, b4.z, acc1[1][i]); acc1[1][i] = fmaf(a1.w, b4.w, acc1[1][i]);
    }
  }
  __syncthreads();

  // ---- GEMM2 (dots_prime RAW) + inline qkv + qk1, two 64-m chunks ----
  float acc2[2][6];
#pragma unroll
  for (int i = 0; i < 6; ++i) { acc2[0][i] = 0.f; acc2[1][i] = 0.f; }
  float qkvr[2][4] = {{0.f,0.f,0.f,0.f},{0.f,0.f,0.f,0.f}};
  float qk1a = 0.f, qk1b = 0.f;
#pragma unroll 1
  for (int ch = 0; ch < 2; ++ch) {
    const int co = ch << 6;
#pragma unroll
    for (int it = 0; it < 2; ++it) {
      const int idx = (it << 8) + tid;
      const int r = idx >> 4, c4 = (idx & 15) << 2;
      *(float4*)&bufA[r][c4] = *(const float4*)&qpb[((size_t)(t0 + r) << 7) + co + c4];
    }
#pragma unroll
    for (int it = 0; it < 6; ++it) {
      const int idx = (it << 8) + tid;
      const int r = idx >> 4, c4 = (idx & 15) << 2;
      const int tg = min(max(k0 + r, 0), TT - 1);
      *(float4*)&bufB[r][c4] = *(const float4*)&kpb[((size_t)tg << 7) + co + c4];
    }
#pragma unroll
    for (int it = 0; it < 4; ++it) {
      const int idx = (it << 8) + tid;
      const int r = idx >> 4, c4 = (idx & 15) << 2;
      *(float4*)&kvs_dT[r * 68 + c4] = *(const float4*)&kvb[((co + r) << 6) + c4];
    }
    __syncthreads();
#pragma unroll
    for (int cc = 0; cc < 16; ++cc) {
      const int col = ((cc + dg) & 15) << 2;
      const float4 a0 = *(const float4*)&bufA[tq][col];
      const float4 a1 = *(const float4*)&bufA[tq + 16][col];
#pragma unroll
      for (int i = 0; i < 6; ++i) {
        const float4 b4 = *(const float4*)&bufB[r6 + i][col];
        acc2[0][i] = fmaf(a0.x, b4.x, acc2[0][i]); acc2[0][i] = fmaf(a0.y, b4.y, acc2[0][i]);
        acc2[0][i] = fmaf(a0.z, b4.z, acc2[0][i]); acc2[0][i] = fmaf(a0.w, b4.w, acc2[0][i]);
        acc2[1][i] = fmaf(a1.x, b4.x, acc2[1][i]); acc2[1][i] = fmaf(a1.y, b4.y, acc2[1][i]);
        acc2[1][i] = fmaf(a1.z, b4.z, acc2[1][i]); acc2[1][i] = fmaf(a1.w, b4.w, acc2[1][i]);
      }
    }
    // qkv: qkvr[r][d] += sum_m qp[row_r][m] * kv[m][d]  (A broadcast, kvs 2-way)
#define QKV_STEP(AX0, AX1, ROW) { \
      const float4 kv4 = *(const float4*)&kvs_dT[(ROW) * 68 + d0c]; \
      qkvr[0][0] = fmaf(AX0, kv4.x, qkvr[0][0]); qkvr[0][1] = fmaf(AX0, kv4.y, qkvr[0][1]); \
      qkvr[0][2] = fmaf(AX0, kv4.z, qkvr[0][2]); qkvr[0][3] = fmaf(AX0, kv4.w, qkvr[0][3]); \
      qkvr[1][0] = fmaf(AX1, kv4.x, qkvr[1][0]); qkvr[1][1] = fmaf(AX1, kv4.y, qkvr[1][1]); \
      qkvr[1][2] = fmaf(AX1, kv4.z, qkvr[1][2]); qkvr[1][3] = fmaf(AX1, kv4.w, qkvr[1][3]); }
#pragma unroll
    for (int mq = 0; mq < 16; ++mq) {
      const int mc = mq << 2;
      const float4 a0 = *(const float4*)&bufA[tq][mc];
      const float4 a1 = *(const float4*)&bufA[tq + 16][mc];
      QKV_STEP(a0.x, a1.x, mc + 0)
      QKV_STEP(a0.y, a1.y, mc + 1)
      QKV_STEP(a0.z, a1.z, mc + 2)
      QKV_STEP(a0.w, a1.w, mc + 3)
    }
#undef QKV_STEP
#pragma unroll
    for (int i = 0; i < 4; ++i) {
      const int m = dg + (i << 4);
      qk1a = fmaf(bufA[tq][m], ksum_s[co + m], qk1a);
      qk1b = fmaf(bufA[tq + 16][m], ksum_s[co + m], qk1b);
    }
    __syncthreads();
  }

  // ---- stage v->B (bufB/kvs reads all done) ----
#pragma unroll
  for (int it = 0; it < 6; ++it) {
    const int idx = (it << 8) + tid;
    const int r = idx >> 4, c4 = (idx & 15) << 2;
    const int tg = min(max(k0 + r, 0), TT - 1);
    *(float4*)&bufB[r][c4] = *(const float4*)&Vbase[(size_t)tg * 512 + c4];
  }

  // ---- P3: masking + reductions + log-space norm + dots (dT overlays kvs) ----
  float* dT = kvs_dT;   // [96][33]
  float psr0, psr1;
  {
    float qktA[6], dptA[6], qktB[6], dptB[6];
#pragma unroll
    for (int i = 0; i < 6; ++i) {
      const int r = r6 + i;
      const int gk = k0 + r;
      const bool gv = (gk >= 0) && (gk < TT);
      const int jA = r - tq;
      const bool vA = gv && (jA >= 0) && (jA < 64);
      qktA[i] = vA ? TEMP * acc1[0][i] : NEGINF;
      dptA[i] = vA ? kscale * acc2[0][i] : 0.f;
      const int jB = jA - 16;
      const bool vB = gv && (jB >= 0) && (jB < 64);
      qktB[i] = vB ? TEMP * acc1[1][i] : NEGINF;
      dptB[i] = vB ? kscale * acc2[1][i] : 0.f;
    }
    float mxA = qktA[0], mxB = qktB[0];
#pragma unroll
    for (int i = 1; i < 6; ++i) { mxA = fmaxf(mxA, qktA[i]); mxB = fmaxf(mxB, qktB[i]); }
    mxA = fmaxf(mxA, __shfl_xor(mxA, 1)); mxB = fmaxf(mxB, __shfl_xor(mxB, 1));
    mxA = fmaxf(mxA, __shfl_xor(mxA, 2)); mxB = fmaxf(mxB, __shfl_xor(mxB, 2));
    mxA = fmaxf(mxA, __shfl_xor(mxA, 4)); mxB = fmaxf(mxB, __shfl_xor(mxB, 4));
    mxA = fmaxf(mxA, __shfl_xor(mxA, 8)); mxB = fmaxf(mxB, __shfl_xor(mxB, 8));

    float seA = 0.f, dpsA = 0.f, seB = 0.f, dpsB = 0.f;
#pragma unroll
    for (int i = 0; i < 6; ++i) {
      seA += __expf(qktA[i] - mxA); dpsA += dptA[i];
      seB += __expf(qktB[i] - mxB); dpsB += dptB[i];
    }
    float q1A = qk1a, q1B = qk1b;
    seA += __shfl_xor(seA, 1); seA += __shfl_xor(seA, 2); seA += __shfl_xor(seA, 4); seA += __shfl_xor(seA, 8);
    seB += __shfl_xor(seB, 1); seB += __shfl_xor(seB, 2); seB += __shfl_xor(seB, 4); seB += __shfl_xor(seB, 8);
    dpsA += __shfl_xor(dpsA, 1); dpsA += __shfl_xor(dpsA, 2); dpsA += __shfl_xor(dpsA, 4); dpsA += __shfl_xor(dpsA, 8);
    dpsB += __shfl_xor(dpsB, 1); dpsB += __shfl_xor(dpsB, 2); dpsB += __shfl_xor(dpsB, 4); dpsB += __shfl_xor(dpsB, 8);
    q1A += __shfl_xor(q1A, 1); q1A += __shfl_xor(q1A, 2); q1A += __shfl_xor(q1A, 4); q1A += __shfl_xor(q1A, 8);
    q1B += __shfl_xor(q1B, 1); q1B += __shfl_xor(q1B, 2); q1B += __shfl_xor(q1B, 4); q1B += __shfl_xor(q1B, 8);

    const float plsA = pls_s[tq], plsB = pls_s[tq + 16];
    const float lseA = mxA + __logf(seA);
    const float lseB = mxB + __logf(seB);
    const float lrA = fmaxf(q1A - dpsA, 1e-24f);
    const float lrB = fmaxf(q1B - dpsB, 1e-24f);
    const float lrlA = __logf(lrA) + plsA;
    const float lrlB = __logf(lrB) + plsB;
    const float aA = fmaxf(lseA, lrlA), bA = fminf(lseA, lrlA);
    const float aB = fmaxf(lseB, lrlB), bB = fminf(lseB, lrlB);
    const float lnA = aA + log1pf(__expf(bA - aA));
    const float lnB = aB + log1pf(__expf(bB - aB));
    psr0 = __expf(plsA - lnA);
    psr1 = __expf(plsB - lnB);
#pragma unroll
    for (int i = 0; i < 6; ++i) {
      const int r = r6 + i;
      dT[r * 33 + tq]      = __expf(qktA[i] - lnA) - dptA[i] * psr0;
      dT[r * 33 + tq + 16] = __expf(qktB[i] - lnB) - dptB[i] * psr1;
    }
  }
  __syncthreads();

  // ---- P5: out_local = dots @ v_win + qkvr * ps ----
  {
    float oA0 = 0.f, oA1 = 0.f, oA2 = 0.f, oA3 = 0.f;
    float oB0 = 0.f, oB1 = 0.f, oB2 = 0.f, oB3 = 0.f;
#pragma unroll 8
    for (int j = 0; j < 64; ++j) {
      const int ra = tq + j;
      const float dva = dT[ra * 33 + tq];
      const float4 va = *(const float4*)&bufB[ra][d0c];
      oA0 = fmaf(dva, va.x, oA0); oA1 = fmaf(dva, va.y, oA1);
      oA2 = fmaf(dva, va.z, oA2); oA3 = fmaf(dva, va.w, oA3);
      const int rb = tq + 16 + j;
      const float dvb = dT[rb * 33 + tq + 16];
      const float4 vb = *(const float4*)&bufB[rb][d0c];
      oB0 = fmaf(dvb, vb.x, oB0); oB1 = fmaf(dvb, vb.y, oB1);
      oB2 = fmaf(dvb, vb.z, oB2); oB3 = fmaf(dvb, vb.w, oB3);
    }
    oA0 = fmaf(qkvr[0][0], psr0, oA0); oA1 = fmaf(qkvr[0][1], psr0, oA1);
    oA2 = fmaf(qkvr[0][2], psr0, oA2); oA3 = fmaf(qkvr[0][3], psr0, oA3);
    oB0 = fmaf(qkvr[1][0], psr1, oB0); oB1 = fmaf(qkvr[1][1], psr1, oB1);
    oB2 = fmaf(qkvr[1][2], psr1, oB2); oB3 = fmaf(qkvr[1][3], psr1, oB3);
    float* obA = out + ((((size_t)b * TT + t0 + tq) * HH + h) << 6) + d0c;
    float* obB = out + ((((size_t)b * TT + t0 + tq + 16) * HH + h) << 6) + d0c;
    *(float4*)obA = make_float4(oA0, oA1, oA2, oA3);
    *(float4*)obB = make_float4(oB0, oB1, oB2, oB3);
  }
}

extern "C" void kernel_launch(void* const* d_in, const int* in_sizes, int n_in,
                              void* d_out, int out_size, void* d_ws, size_t ws_size,
                              hipStream_t stream) {
  (void)in_sizes; (void)n_in; (void)out_size; (void)ws_size;
  const float* Q    = (const float*)d_in[0];
  const float* K    = (const float*)d_in[1];
  const float* V    = (const float*)d_in[2];
  const float* proj = (const float*)d_in[3];
  float* out = (float*)d_out;
  char* ws = (char*)d_ws;

  float* qp    = (float*)(ws + OFF_QP);
  float* kf    = (float*)(ws + OFF_KF);
  float* kvp   = (float*)(ws + OFF_KVP);
  float* kv    = (float*)(ws + OFF_KV);
  float* ksum  = (float*)(ws + OFF_KSUM);
  float* qstab = (float*)(ws + OFF_QSTAB);
  float* ksump = (float*)(ws + OFF_KSUMP);
  float* wtmax = (float*)(ws + OFF_WTMAX);

  feat_kernel<<<512, 256, 0, stream>>>(Q, K, proj, qp, kf, qstab, wtmax);
  kv_partial<<<256, 256, 0, stream>>>(V, kf, kvp, ksump);
  kv_reduce<<<136, 256, 0, stream>>>(kvp, ksump, wtmax, kv, ksum);
  band_kernel<<<512, 256, 0, stream>>>(Q, K, V, qp, kf, kv, ksum, qstab, wtmax, out);
}

// Round 7
// 68.224 us; speedup vs baseline: 3.6321x; 1.1680x over previous
//
#include <hip/hip_runtime.h>

#define TT 1024
#define HH 8
#define EE 64
#define MM 128
#define NBH 16

#define NORMALIZER 0.35355339059327379f
#define RSQRT_M    0.08838834764831845f
#define TEMP       0.125f
#define NEGINF     -1e24f

typedef __attribute__((ext_vector_type(8))) short short8v;
typedef __attribute__((ext_vector_type(4))) float f32x4;
#define MFMA_BF16 __builtin_amdgcn_mfma_f32_16x16x32_bf16

// ws byte offsets
#define OFF_QP    0u            // [BH][T][M] f32  8 MB   q_prime (scaled)
#define OFF_KF    8388608u      // [BH][T][M] f32  8 MB   exp(logfeat_k) RAW
#define OFF_KVP   16777216u     // [BH][16][M][E] f32 8 MB unscaled kv partials
#define OFF_KV    25165824u     // [BH][M][E] f32  512 KB (scaled)
#define OFF_KSUM  25690112u     // [BH][M]    f32  8 KB   (scaled)
#define OFF_QSTAB 25698304u     // [BH][T]    f32  64 KB
#define OFF_KSUMP 25763840u     // [BH][16][M] f32 128 KB (unscaled partials)
#define OFF_WTMAX 25894912u     // [BH][16]   f32  1 KB   per-tile k logfeat max

__device__ __forceinline__ unsigned short f2bf(float x) {
  unsigned u = __float_as_uint(x);
  u += 0x7FFFu + ((u >> 16) & 1u);
  return (unsigned short)(u >> 16);
}
__device__ __forceinline__ float bf2f(unsigned short h) {
  return __uint_as_float(((unsigned)h) << 16);
}
__device__ __forceinline__ void f2bf2(float x, unsigned short& hi, unsigned short& lo) {
  hi = f2bf(x);
  lo = f2bf(x - bf2f(hi));
}
// MFMA A/B fragment load: row-major [row][K] bf16 buffer, LD in elems.
__device__ __forceinline__ short8v ldfrag(const short* buf, int ld, int rowbase,
                                          int kbase, int lane) {
  return *(const short8v*)&buf[(rowbase + (lane & 15)) * ld + kbase + ((lane >> 4) << 3)];
}

// ---------------------------------------------------------------------------
// Kernel A: FAVOR+ features. Grid 512 = 2 paths * 16 bh * 16 rowtiles(64). (R5)
// ---------------------------------------------------------------------------
__global__ __launch_bounds__(256, 2) void feat_kernel(
    const float* __restrict__ Q, const float* __restrict__ K,
    const float* __restrict__ proj,
    float* __restrict__ qp, float* __restrict__ kf,
    float* __restrict__ qstab, float* __restrict__ wtmax)
{
  __shared__ float xsT[64][65];   // [e][row]
  __shared__ float Mh[64][4];

  const int bid  = blockIdx.x;
  const int path = bid >> 8;          // 0=q, 1=k
  const int bh   = (bid >> 4) & 15;
  const int rt   = bid & 15;
  const int b = bh >> 3, h = bh & 7;
  const int t0 = rt << 6;
  const int tid = threadIdx.x;

  const float* x = path ? K : Q;
  const float* xbase = x + (((size_t)b * TT * HH + h) << 6);
#pragma unroll
  for (int it = 0; it < 4; ++it) {
    const int idx = (it << 8) + tid;
    const int r = idx >> 4, c = (idx & 15) << 2;
    const float4 f4 = *(const float4*)&xbase[(size_t)(t0 + r) * 512 + c];
    xsT[c + 0][r] = f4.x; xsT[c + 1][r] = f4.y;
    xsT[c + 2][r] = f4.z; xsT[c + 3][r] = f4.w;
  }
  __syncthreads();

  const int lane = tid & 63;
  const int w = __builtin_amdgcn_readfirstlane(tid >> 6);
  float xv[64];
  float diag = 0.f;
#pragma unroll
  for (int c = 0; c < 64; ++c) { xv[c] = xsT[c][lane]; diag = fmaf(xv[c], xv[c], diag); }
  diag *= 0.0625f;   // 0.5*temp

  float lf[32];
  float mx = -3e30f;
  const int mbase = w << 5;
  for (int mm = 0; mm < 32; ++mm) {
    const float* pr = proj + ((mbase + mm) << 6);
    float a0 = 0.f, a1 = 0.f;
#pragma unroll
    for (int c = 0; c < 64; c += 2) {
      a0 = fmaf(xv[c], pr[c], a0);
      a1 = fmaf(xv[c + 1], pr[c + 1], a1);
    }
    const float v = fmaf(NORMALIZER, a0 + a1, -diag);
    lf[mm] = v;
    mx = fmaxf(mx, v);
  }
  Mh[lane][w] = mx;
  __syncthreads();
  const float m0 = fmaxf(fmaxf(Mh[lane][0], Mh[lane][1]), fmaxf(Mh[lane][2], Mh[lane][3]));

  float ov[32];
  if (path == 0) {
#pragma unroll
    for (int mm = 0; mm < 32; ++mm) ov[mm] = RSQRT_M * __expf(lf[mm] - m0);
    if (w == 0) qstab[(size_t)bh * TT + t0 + lane] = m0;
  } else {
#pragma unroll
    for (int mm = 0; mm < 32; ++mm) ov[mm] = __expf(lf[mm]);
    if (w == 0) {
      float bm = m0;
#pragma unroll
      for (int off = 1; off < 64; off <<= 1) bm = fmaxf(bm, __shfl_xor(bm, off));
      if (lane == 0) wtmax[(bh << 4) + rt] = bm;
    }
  }
  float* dst = (path ? kf : qp) + (((size_t)bh * TT + t0 + lane) << 7) + mbase;
#pragma unroll
  for (int q4 = 0; q4 < 8; ++q4)
    *(float4*)&dst[q4 << 2] =
        make_float4(ov[q4 * 4], ov[q4 * 4 + 1], ov[q4 * 4 + 2], ov[q4 * 4 + 3]);
}

// ---------------------------------------------------------------------------
// Kernel B: UNSCALED partial kv + ksum per 64-row s-tile. Grid 256. (R5)
// ---------------------------------------------------------------------------
__global__ __launch_bounds__(256, 2) void kv_partial(
    const float* __restrict__ V, const float* __restrict__ kf,
    float* __restrict__ kvp, float* __restrict__ ksump)
{
  __shared__ __align__(16) float smem[64 * 132 + 64 * 68];
  float (*kp_s)[132] = (float(*)[132])smem;
  float (*vs)[68] = (float(*)[68])(smem + 64 * 132);

  const int bid = blockIdx.x;
  const int bh = bid >> 4, st = bid & 15;
  const int b = bh >> 3, h = bh & 7;
  const int tid = threadIdx.x;
  const int row0 = st << 6;
  const size_t base_kf = ((size_t)bh * TT + row0) << 7;

#pragma unroll
  for (int it = 0; it < 8; ++it) {
    const int idx = (it << 10) + (tid << 2);
    const int r = idx >> 7, c = idx & 127;
    *(float4*)&kp_s[r][c] = *(const float4*)&kf[base_kf + idx];
  }
#pragma unroll
  for (int it = 0; it < 4; ++it) {
    const int idx = (it << 10) + (tid << 2);
    const int r = idx >> 6, c = idx & 63;
    *(float4*)&vs[r][c] = *(const float4*)(V + ((((size_t)b * TT + row0 + r) * HH + h) << 6) + c);
  }
  __syncthreads();

  if (tid < 128) {
    float s = 0.f;
    for (int ss = 0; ss < 64; ++ss) s += kp_s[ss][tid];
    ksump[(bid << 7) + tid] = s;
  }

  const int h2 = tid >> 7;
  const int m0 = ((tid & 127) >> 3) << 3;
  const int d0 = (tid & 7) << 3;
  float acc[8][8];
#pragma unroll
  for (int i = 0; i < 8; ++i)
#pragma unroll
    for (int j = 0; j < 8; ++j) acc[i][j] = 0.f;

  const int s0 = h2 << 5;
  for (int ss = s0; ss < s0 + 32; ++ss) {
    const float4 k0v = *(const float4*)&kp_s[ss][m0];
    const float4 k1v = *(const float4*)&kp_s[ss][m0 + 4];
    const float4 v0v = *(const float4*)&vs[ss][d0];
    const float4 v1v = *(const float4*)&vs[ss][d0 + 4];
    const float km[8] = {k0v.x,k0v.y,k0v.z,k0v.w,k1v.x,k1v.y,k1v.z,k1v.w};
    const float vd[8] = {v0v.x,v0v.y,v0v.z,v0v.w,v1v.x,v1v.y,v1v.z,v1v.w};
#pragma unroll
    for (int i = 0; i < 8; ++i)
#pragma unroll
      for (int j = 0; j < 8; ++j) acc[i][j] = fmaf(km[i], vd[j], acc[i][j]);
  }
  __syncthreads();
  float (*kvm)[68] = (float(*)[68])smem;
  if (h2 == 0) {
#pragma unroll
    for (int i = 0; i < 8; ++i)
#pragma unroll
      for (int j = 0; j < 8; ++j) kvm[m0 + i][d0 + j] = acc[i][j];
  }
  __syncthreads();
  if (h2 == 1) {
#pragma unroll
    for (int i = 0; i < 8; ++i)
#pragma unroll
      for (int j = 0; j < 8; ++j) kvm[m0 + i][d0 + j] += acc[i][j];
  }
  __syncthreads();
  float* kvb = kvp + ((size_t)bid << 13);
#pragma unroll
  for (int it = 0; it < 8; ++it) {
    const int idx = (it << 10) + (tid << 2);
    const int m = idx >> 6, d = idx & 63;
    *(float4*)&kvb[idx] = make_float4(kvm[m][d], kvm[m][d + 1], kvm[m][d + 2], kvm[m][d + 3]);
  }
}

// ---------------------------------------------------------------------------
// Kernel B2: reduce 16 partials, apply scale. Grid 136. (R5)
// ---------------------------------------------------------------------------
__global__ __launch_bounds__(256, 4) void kv_reduce(
    const float* __restrict__ kvp, const float* __restrict__ ksump,
    const float* __restrict__ wtmax,
    float* __restrict__ kv, float* __restrict__ ksum)
{
  const int bid = blockIdx.x;
  const int tid = threadIdx.x;
  if (bid < 128) {
    const int g = (bid << 10) + (tid << 2);
    const int bh = g >> 13, idx = g & 8191;
    float kml = wtmax[bh << 4];
#pragma unroll
    for (int i = 1; i < 16; ++i) kml = fmaxf(kml, wtmax[(bh << 4) + i]);
    const float scale = RSQRT_M * __expf(-kml);
    float4 s = make_float4(0.f, 0.f, 0.f, 0.f);
#pragma unroll
    for (int p = 0; p < 16; ++p) {
      const float4 v = *(const float4*)&kvp[((((size_t)bh << 4) + p) << 13) + idx];
      s.x += v.x; s.y += v.y; s.z += v.z; s.w += v.w;
    }
    s.x *= scale; s.y *= scale; s.z *= scale; s.w *= scale;
    *(float4*)&kv[((size_t)bh << 13) + idx] = s;
  } else {
    const int g = ((bid - 128) << 8) + tid;
    const int bh = g >> 7, m = g & 127;
    float kml = wtmax[bh << 4];
#pragma unroll
    for (int i = 1; i < 16; ++i) kml = fmaxf(kml, wtmax[(bh << 4) + i]);
    const float scale = RSQRT_M * __expf(-kml);
    float s = 0.f;
#pragma unroll
    for (int p = 0; p < 16; ++p) s += ksump[(((bh << 4) + p) << 7) + m];
    ksum[(bh << 7) + m] = s * scale;
  }
}

// ---------------------------------------------------------------------------
// Kernel D: banded local attention via DOUBLE-BF16 (hi+lo, 3-product) MFMA.
// Grid 256 = 16 bh * 16 tiles(64 q, window 128). 78.6 KB LDS -> 2 blocks/CU.
// LDS union (shorts): qA_hi 0, qA_lo 4608, B_hi 9216, B_lo 18432,
//   kvT_hi 27648 (80x72), kvT_lo 33408 (80x72), end 39168.
// Phase C overlay: VT_hi 0, VT_lo 8704, dots_hi 17408, dots_lo 26112 (LD 136).
// ---------------------------------------------------------------------------
__global__ __launch_bounds__(256, 2) void band_kernel(
    const float* __restrict__ Q, const float* __restrict__ K,
    const float* __restrict__ V,
    const float* __restrict__ qp, const float* __restrict__ kp,
    const float* __restrict__ kv, const float* __restrict__ ksum,
    const float* __restrict__ qstab, const float* __restrict__ wtmax,
    float* __restrict__ out)
{
  __shared__ __align__(16) short smem[39168];
  __shared__ float pls_s[64];
  short* const qA_hi = smem;
  short* const qA_lo = smem + 4608;
  short* const B_hi  = smem + 9216;
  short* const B_lo  = smem + 18432;
  short* const kvT_hi = smem + 27648;
  short* const kvT_lo = smem + 33408;
  short* const VT_hi  = smem;            // phase C
  short* const VT_lo  = smem + 8704;
  short* const dots_hi = smem + 17408;
  short* const dots_lo = smem + 26112;

  const int g = blockIdx.x;
  const int lg = ((g & 7) << 5) | (g >> 3);          // XCD chunk swizzle (256 wgs)
  const int bh = lg >> 4, tile = lg & 15;
  const int b = bh >> 3, h = bh & 7;
  const int t0 = tile << 6;
  const int k0 = t0 - 32;
  const int tid = threadIdx.x;
  const int lane = tid & 63;
  const int wq = __builtin_amdgcn_readfirstlane(tid >> 6);

  float kml = wtmax[bh << 4];
#pragma unroll
  for (int i = 1; i < 16; ++i) kml = fmaxf(kml, wtmax[(bh << 4) + i]);
  const float kscale = RSQRT_M * __expf(-kml);

  const float* Qbase = Q + (((size_t)b * TT * HH + h) << 6);
  const float* Kbase = K + (((size_t)b * TT * HH + h) << 6);
  const float* Vbase = V + (((size_t)b * TT * HH + h) << 6);
  const float* qpb = qp + (((size_t)bh * TT) << 7);
  const float* kpb = kp + (((size_t)bh * TT) << 7);
  const float* kvb = kv + ((size_t)bh << 13);
  const float* ksb = ksum + (bh << 7);

  // ---- Phase A: stage q hi/lo (64x64) and K hi/lo (128x64), pls ----
#pragma unroll
  for (int it = 0; it < 4; ++it) {
    const int idx = (it << 8) + tid;
    const int r = idx >> 4, cc = (idx & 15) << 2;
    const float4 v = *(const float4*)&Qbase[(size_t)(t0 + r) * 512 + cc];
    short4 hi4, lo4;
    f2bf2(v.x, (unsigned short&)hi4.x, (unsigned short&)lo4.x);
    f2bf2(v.y, (unsigned short&)hi4.y, (unsigned short&)lo4.y);
    f2bf2(v.z, (unsigned short&)hi4.z, (unsigned short&)lo4.z);
    f2bf2(v.w, (unsigned short&)hi4.w, (unsigned short&)lo4.w);
    *(short4*)&qA_hi[r * 72 + cc] = hi4;
    *(short4*)&qA_lo[r * 72 + cc] = lo4;
  }
#pragma unroll
  for (int it = 0; it < 8; ++it) {
    const int idx = (it << 8) + tid;
    const int r = idx >> 4, cc = (idx & 15) << 2;
    const int tg = min(max(k0 + r, 0), TT - 1);
    const float4 v = *(const float4*)&Kbase[(size_t)tg * 512 + cc];
    short4 hi4, lo4;
    f2bf2(v.x, (unsigned short&)hi4.x, (unsigned short&)lo4.x);
    f2bf2(v.y, (unsigned short&)hi4.y, (unsigned short&)lo4.y);
    f2bf2(v.z, (unsigned short&)hi4.z, (unsigned short&)lo4.z);
    f2bf2(v.w, (unsigned short&)hi4.w, (unsigned short&)lo4.w);
    *(short4*)&B_hi[r * 72 + cc] = hi4;
    *(short4*)&B_lo[r * 72 + cc] = lo4;
  }
  if (tid < 64) pls_s[tid] = qstab[(size_t)bh * TT + t0 + tid] + kml;
  __syncthreads();

  // ---- GEMM1: S = q . K^T (3-product) ----
  f32x4 C1[8];
#pragma unroll
  for (int nt = 0; nt < 8; ++nt) C1[nt] = (f32x4){0.f, 0.f, 0.f, 0.f};
  {
    const short8v qh0 = ldfrag(qA_hi, 72, wq << 4, 0, lane);
    const short8v qh1 = ldfrag(qA_hi, 72, wq << 4, 32, lane);
    const short8v ql0 = ldfrag(qA_lo, 72, wq << 4, 0, lane);
    const short8v ql1 = ldfrag(qA_lo, 72, wq << 4, 32, lane);
#pragma unroll
    for (int nt = 0; nt < 8; ++nt) {
      const short8v bh0 = ldfrag(B_hi, 72, nt << 4, 0, lane);
      const short8v bh1 = ldfrag(B_hi, 72, nt << 4, 32, lane);
      C1[nt] = MFMA_BF16(qh0, bh0, C1[nt], 0, 0, 0);
      C1[nt] = MFMA_BF16(qh1, bh1, C1[nt], 0, 0, 0);
      C1[nt] = MFMA_BF16(qh0, ldfrag(B_lo, 72, nt << 4, 0, lane), C1[nt], 0, 0, 0);
      C1[nt] = MFMA_BF16(qh1, ldfrag(B_lo, 72, nt << 4, 32, lane), C1[nt], 0, 0, 0);
      C1[nt] = MFMA_BF16(ql0, bh0, C1[nt], 0, 0, 0);
      C1[nt] = MFMA_BF16(ql1, bh1, C1[nt], 0, 0, 0);
    }
  }
  __syncthreads();

  // ---- GEMM2 (q' . kp^T) + qkv (q' . kv) + qk1, two 64-m chunks ----
  f32x4 C2[8], C3[5];
#pragma unroll
  for (int nt = 0; nt < 8; ++nt) C2[nt] = (f32x4){0.f, 0.f, 0.f, 0.f};
#pragma unroll
  for (int nt = 0; nt < 5; ++nt) C3[nt] = (f32x4){0.f, 0.f, 0.f, 0.f};

#pragma unroll 1
  for (int c = 0; c < 2; ++c) {
    const int co = c << 6;
    // qp chunk hi/lo -> qA planes
#pragma unroll
    for (int it = 0; it < 4; ++it) {
      const int idx = (it << 8) + tid;
      const int r = idx >> 4, cc = (idx & 15) << 2;
      const float4 v = *(const float4*)&qpb[((size_t)(t0 + r) << 7) + co + cc];
      short4 hi4, lo4;
      f2bf2(v.x, (unsigned short&)hi4.x, (unsigned short&)lo4.x);
      f2bf2(v.y, (unsigned short&)hi4.y, (unsigned short&)lo4.y);
      f2bf2(v.z, (unsigned short&)hi4.z, (unsigned short&)lo4.z);
      f2bf2(v.w, (unsigned short&)hi4.w, (unsigned short&)lo4.w);
      *(short4*)&qA_hi[r * 72 + cc] = hi4;
      *(short4*)&qA_lo[r * 72 + cc] = lo4;
    }
    // kp chunk hi/lo -> B planes
#pragma unroll
    for (int it = 0; it < 8; ++it) {
      const int idx = (it << 8) + tid;
      const int r = idx >> 4, cc = (idx & 15) << 2;
      const int tg = min(max(k0 + r, 0), TT - 1);
      const float4 v = *(const float4*)&kpb[((size_t)tg << 7) + co + cc];
      short4 hi4, lo4;
      f2bf2(v.x, (unsigned short&)hi4.x, (unsigned short&)lo4.x);
      f2bf2(v.y, (unsigned short&)hi4.y, (unsigned short&)lo4.y);
      f2bf2(v.z, (unsigned short&)hi4.z, (unsigned short&)lo4.z);
      f2bf2(v.w, (unsigned short&)hi4.w, (unsigned short&)lo4.w);
      *(short4*)&B_hi[r * 72 + cc] = hi4;
      *(short4*)&B_lo[r * 72 + cc] = lo4;
    }
    // kv^T chunk hi/lo -> kvT planes rows 0..63 (row=d, col=m_local)
    {
      const int mloc = tid >> 2, db = (tid & 3) << 4;
      const float4* kr = (const float4*)(kvb + ((co + mloc) << 6) + db);
#pragma unroll
      for (int i2 = 0; i2 < 4; ++i2) {
        const float4 v = kr[i2];
        const int dr = db + (i2 << 2);
        unsigned short hs, ls;
        f2bf2(v.x, hs, ls); kvT_hi[(dr + 0) * 72 + mloc] = hs; kvT_lo[(dr + 0) * 72 + mloc] = ls;
        f2bf2(v.y, hs, ls); kvT_hi[(dr + 1) * 72 + mloc] = hs; kvT_lo[(dr + 1) * 72 + mloc] = ls;
        f2bf2(v.z, hs, ls); kvT_hi[(dr + 2) * 72 + mloc] = hs; kvT_lo[(dr + 2) * 72 + mloc] = ls;
        f2bf2(v.w, hs, ls); kvT_hi[(dr + 3) * 72 + mloc] = hs; kvT_lo[(dr + 3) * 72 + mloc] = ls;
      }
    }
    // ksum hi/lo in kvT_hi rows 64/65; kvT_lo rows 64/65 zeroed
    if (tid < 64) {
      const float x = ksb[co + tid];
      unsigned short hs, ls;
      f2bf2(x, hs, ls);
      kvT_hi[64 * 72 + tid] = hs;
      kvT_hi[65 * 72 + tid] = ls;
      kvT_lo[64 * 72 + tid] = 0;
      kvT_lo[65 * 72 + tid] = 0;
    }
    __syncthreads();

    const short8v ph0 = ldfrag(qA_hi, 72, wq << 4, 0, lane);
    const short8v ph1 = ldfrag(qA_hi, 72, wq << 4, 32, lane);
    const short8v pl0 = ldfrag(qA_lo, 72, wq << 4, 0, lane);
    const short8v pl1 = ldfrag(qA_lo, 72, wq << 4, 32, lane);
#pragma unroll
    for (int nt = 0; nt < 8; ++nt) {
      const short8v bh0 = ldfrag(B_hi, 72, nt << 4, 0, lane);
      const short8v bh1 = ldfrag(B_hi, 72, nt << 4, 32, lane);
      C2[nt] = MFMA_BF16(ph0, bh0, C2[nt], 0, 0, 0);
      C2[nt] = MFMA_BF16(ph1, bh1, C2[nt], 0, 0, 0);
      C2[nt] = MFMA_BF16(ph0, ldfrag(B_lo, 72, nt << 4, 0, lane), C2[nt], 0, 0, 0);
      C2[nt] = MFMA_BF16(ph1, ldfrag(B_lo, 72, nt << 4, 32, lane), C2[nt], 0, 0, 0);
      C2[nt] = MFMA_BF16(pl0, bh0, C2[nt], 0, 0, 0);
      C2[nt] = MFMA_BF16(pl1, bh1, C2[nt], 0, 0, 0);
    }
#pragma unroll
    for (int nt = 0; nt < 5; ++nt) {
      const short8v kh0 = ldfrag(kvT_hi, 72, nt << 4, 0, lane);
      const short8v kh1 = ldfrag(kvT_hi, 72, nt << 4, 32, lane);
      C3[nt] = MFMA_BF16(ph0, kh0, C3[nt], 0, 0, 0);
      C3[nt] = MFMA_BF16(ph1, kh1, C3[nt], 0, 0, 0);
      C3[nt] = MFMA_BF16(ph0, ldfrag(kvT_lo, 72, nt << 4, 0, lane), C3[nt], 0, 0, 0);
      C3[nt] = MFMA_BF16(ph1, ldfrag(kvT_lo, 72, nt << 4, 32, lane), C3[nt], 0, 0, 0);
      C3[nt] = MFMA_BF16(pl0, kh0, C3[nt], 0, 0, 0);
      C3[nt] = MFMA_BF16(pl1, kh1, C3[nt], 0, 0, 0);
    }
    __syncthreads();
  }

  // ---- Phase C: stage V^T hi/lo (rows d, cols j, LD 136) ----
  {
    const int jl = tid >> 1, db = (tid & 1) << 5;
    const int tg = min(max(k0 + jl, 0), TT - 1);
    const float4* vr = (const float4*)&Vbase[(size_t)tg * 512 + db];
#pragma unroll
    for (int i2 = 0; i2 < 8; ++i2) {
      const float4 v = vr[i2];
      const int dr = db + (i2 << 2);
      unsigned short hs, ls;
      f2bf2(v.x, hs, ls); VT_hi[(dr + 0) * 136 + jl] = hs; VT_lo[(dr + 0) * 136 + jl] = ls;
      f2bf2(v.y, hs, ls); VT_hi[(dr + 1) * 136 + jl] = hs; VT_lo[(dr + 1) * 136 + jl] = ls;
      f2bf2(v.z, hs, ls); VT_hi[(dr + 2) * 136 + jl] = hs; VT_lo[(dr + 2) * 136 + jl] = ls;
      f2bf2(v.w, hs, ls); VT_hi[(dr + 3) * 136 + jl] = hs; VT_lo[(dr + 3) * 136 + jl] = ls;
    }
  }

  // ---- P3: per-lane softmax / log-norm, dots hi/lo -> LDS ----
  float psr[4];
  const int lrow = (lane >> 4) << 2;
  const int lcol = lane & 15;
#pragma unroll
  for (int r = 0; r < 4; ++r) {
    const int ql = (wq << 4) + lrow + r;
    float qkt[8], dpt[8];
    float mx = -3e30f;
#pragma unroll
    for (int nt = 0; nt < 8; ++nt) {
      const int kr = (nt << 4) + lcol;
      const int j = kr - ql;
      const int gk = k0 + kr;
      const bool vv = (j >= 0) && (j < 64) && (gk >= 0) && (gk < TT);
      qkt[nt] = vv ? TEMP * C1[nt][r] : NEGINF;
      dpt[nt] = vv ? kscale * C2[nt][r] : 0.f;
      mx = fmaxf(mx, qkt[nt]);
    }
    mx = fmaxf(mx, __shfl_xor(mx, 1));
    mx = fmaxf(mx, __shfl_xor(mx, 2));
    mx = fmaxf(mx, __shfl_xor(mx, 4));
    mx = fmaxf(mx, __shfl_xor(mx, 8));
    float se = 0.f, dps = 0.f;
#pragma unroll
    for (int nt = 0; nt < 8; ++nt) {
      se += __expf(qkt[nt] - mx);
      dps += dpt[nt];
    }
    se += __shfl_xor(se, 1); se += __shfl_xor(se, 2);
    se += __shfl_xor(se, 4); se += __shfl_xor(se, 8);
    dps += __shfl_xor(dps, 1); dps += __shfl_xor(dps, 2);
    dps += __shfl_xor(dps, 4); dps += __shfl_xor(dps, 8);
    const float qk1 = __shfl(C3[4][r], lane & 48) + __shfl(C3[4][r], (lane & 48) + 1);

    const float pls = pls_s[ql];
    const float lse = mx + __logf(se);
    const float lr = fmaxf(qk1 - dps, 1e-24f);
    const float lrl = __logf(lr) + pls;
    const float aa = fmaxf(lse, lrl), bb = fminf(lse, lrl);
    const float ln = aa + log1pf(__expf(bb - aa));
    psr[r] = __expf(pls - ln);
#pragma unroll
    for (int nt = 0; nt < 8; ++nt) {
      const float d = __expf(qkt[nt] - ln) - dpt[nt] * psr[r];
      unsigned short hs, ls;
      f2bf2(d, hs, ls);
      dots_hi[ql * 136 + (nt << 4) + lcol] = hs;
      dots_lo[ql * 136 + (nt << 4) + lcol] = ls;
    }
  }
  __syncthreads();

  // ---- PV: out_local = dots . V (3-product) + epilogue ----
  f32x4 D4[4];
#pragma unroll
  for (int nt = 0; nt < 4; ++nt) D4[nt] = (f32x4){0.f, 0.f, 0.f, 0.f};
#pragma unroll
  for (int kk = 0; kk < 4; ++kk) {
    const short8v adh = ldfrag(dots_hi, 136, wq << 4, kk << 5, lane);
    const short8v adl = ldfrag(dots_lo, 136, wq << 4, kk << 5, lane);
#pragma unroll
    for (int nt = 0; nt < 4; ++nt) {
      const short8v vh = ldfrag(VT_hi, 136, nt << 4, kk << 5, lane);
      D4[nt] = MFMA_BF16(adh, vh, D4[nt], 0, 0, 0);
      D4[nt] = MFMA_BF16(adh, ldfrag(VT_lo, 136, nt << 4, kk << 5, lane), D4[nt], 0, 0, 0);
      D4[nt] = MFMA_BF16(adl, vh, D4[nt], 0, 0, 0);
    }
  }
#pragma unroll
  for (int nt = 0; nt < 4; ++nt) {
#pragma unroll
    for (int r = 0; r < 4; ++r) {
      const int ql = (wq << 4) + lrow + r;
      const float val = D4[nt][r] + C3[nt][r] * psr[r];
      out[((((size_t)b * TT + t0 + ql) * HH + h) << 6) + (nt << 4) + lcol] = val;
    }
  }
}

extern "C" void kernel_launch(void* const* d_in, const int* in_sizes, int n_in,
                              void* d_out, int out_size, void* d_ws, size_t ws_size,
                              hipStream_t stream) {
  (void)in_sizes; (void)n_in; (void)out_size; (void)ws_size;
  const float* Q    = (const float*)d_in[0];
  const float* K    = (const float*)d_in[1];
  const float* V    = (const float*)d_in[2];
  const float* proj = (const float*)d_in[3];
  float* out = (float*)d_out;
  char* ws = (char*)d_ws;

  float* qp    = (float*)(ws + OFF_QP);
  float* kf    = (float*)(ws + OFF_KF);
  float* kvp   = (float*)(ws + OFF_KVP);
  float* kv    = (float*)(ws + OFF_KV);
  float* ksum  = (float*)(ws + OFF_KSUM);
  float* qstab = (float*)(ws + OFF_QSTAB);
  float* ksump = (float*)(ws + OFF_KSUMP);
  float* wtmax = (float*)(ws + OFF_WTMAX);

  feat_kernel<<<512, 256, 0, stream>>>(Q, K, proj, qp, kf, qstab, wtmax);
  kv_partial<<<256, 256, 0, stream>>>(V, kf, kvp, ksump);
  kv_reduce<<<136, 256, 0, stream>>>(kvp, ksump, wtmax, kv, ksum);
  band_kernel<<<256, 256, 0, stream>>>(Q, K, V, qp, kf, kv, ksum, qstab, wtmax, out);
}